// Round 7
// baseline (919.849 us; speedup 1.0000x reference)
//
#include <hip/hip_runtime.h>

#define D 128
#define EPS 1e-10f
#define TILE 16
#define WPB 4
#define NBLK 512
#define THR 14.0f

// ---------------------------------------------------------------------------
// PROBE: maximally-dumb pure-read stream (fill/m13 family). Reads x 4 times
// (2 GB), 4-way unrolled independent loads, writes 8 MB to scratch (later
// overwritten by GEMM -> no correctness impact). Exists ONLY to measure this
// machine's attainable pure-read HBM rate in the rocprof table.
// ---------------------------------------------------------------------------
__global__ __launch_bounds__(256) void probe_read_kernel(
    const float4* __restrict__ x4, long long n4, float4* __restrict__ sink) {
    const long long stride  = (long long)gridDim.x * 256;
    const long long stride4 = stride * 4;
    const long long tid = (long long)blockIdx.x * 256 + threadIdx.x;
    float4 a = {0.f, 0.f, 0.f, 0.f};
#pragma unroll 1
    for (int r = 0; r < 4; r++) {
        for (long long i = tid; i < n4; i += stride4) {
            float4 v0 = x4[i];
            float4 v1, v2, v3;
            bool b1 = i + stride < n4, b2 = i + 2 * stride < n4,
                 b3 = i + 3 * stride < n4;
            if (b1) v1 = x4[i + stride];
            if (b2) v2 = x4[i + 2 * stride];
            if (b3) v3 = x4[i + 3 * stride];
            a.x += v0.x; a.y += v0.y; a.z += v0.z; a.w += v0.w;
            if (b1) { a.x += v1.x; a.y += v1.y; a.z += v1.z; a.w += v1.w; }
            if (b2) { a.x += v2.x; a.y += v2.y; a.z += v2.z; a.w += v2.w; }
            if (b3) { a.x += v3.x; a.y += v3.y; a.z += v3.z; a.w += v3.w; }
        }
    }
    sink[tid] = a;
}

// ---------------------------------------------------------------------------
// async global -> LDS, 16B per lane (dest = base + lane*16, linear)
// ---------------------------------------------------------------------------
__device__ __forceinline__ void gload16(const float* g, float* l) {
    __builtin_amdgcn_global_load_lds(
        (const __attribute__((address_space(1))) void*)g,
        (__attribute__((address_space(3))) void*)l, 16, 0, 0);
}

// scalar load of row_ptr[idx], row_ptr[idx+1] (lgkmcnt path — keeps vmcnt
// counting clean for the gload_lds pipeline)
__device__ __forceinline__ unsigned long long sload2(const int* rp, int idx) {
    unsigned long long r;
    int off = __builtin_amdgcn_readfirstlane(idx << 2);
    asm volatile("s_load_dwordx2 %0, %1, %2\n\ts_waitcnt lgkmcnt(0)"
                 : "=s"(r) : "s"(rp), "s"(off) : "memory");
    return r;
}

__device__ __forceinline__ void wait_vm(int nn) {
    switch (nn) {
    case 0:  asm volatile("s_waitcnt vmcnt(0)" ::: "memory"); break;
    case 1:  asm volatile("s_waitcnt vmcnt(1)" ::: "memory"); break;
    case 2:  asm volatile("s_waitcnt vmcnt(2)" ::: "memory"); break;
    case 3:  asm volatile("s_waitcnt vmcnt(3)" ::: "memory"); break;
    case 8:  asm volatile("s_waitcnt vmcnt(8)" ::: "memory"); break;
    case 9:  asm volatile("s_waitcnt vmcnt(9)" ::: "memory"); break;
    case 10: asm volatile("s_waitcnt vmcnt(10)" ::: "memory"); break;
    case 11: asm volatile("s_waitcnt vmcnt(11)" ::: "memory"); break;
    default: asm volatile("s_waitcnt vmcnt(0)" ::: "memory"); break;
    }
}

// bit-mixed dim-group -> slot permutation (keeps every LDS phase <=2-way):
// delta(d) = (d&24) | ((d + 2*(d>>3)) & 7);  inverse: q=u>>3, low=(u-2q)&7
__device__ __forceinline__ int dperm(int d) {
    return (d & 24) | ((d + 2 * (d >> 3)) & 7);
}
__device__ __forceinline__ int dperm_inv(int u) {
    int q = u >> 3;
    return (q << 3) | ((u - 2 * q) & 7);
}

// ---------------------------------------------------------------------------
// K1: row_ptr via binary search (node2graph sorted)
// ---------------------------------------------------------------------------
__global__ void rowptr_kernel(const int* __restrict__ n2g, int N_, int B_,
                              int* __restrict__ row_ptr) {
    int b = blockIdx.x * 256 + threadIdx.x;
    if (b > B_) return;
    if (b == B_) { row_ptr[b] = N_; return; }
    int lo = 0, hi = N_;
    while (lo < hi) {
        int mid = (lo + hi) >> 1;
        if (n2g[mid] < b) lo = mid + 1; else hi = mid;
    }
    row_ptr[b] = lo;
}

// ---------------------------------------------------------------------------
// K2: b_sum = b_ih + b_hh; step-1 constants h1, c1
// ---------------------------------------------------------------------------
__global__ void init_consts_kernel(const float* __restrict__ b_ih,
                                   const float* __restrict__ b_hh,
                                   float* __restrict__ b_sum,
                                   float* __restrict__ c1,
                                   float* __restrict__ h1) {
    int t = threadIdx.x;  // 512 threads, 1 block
    __shared__ float bs[512];
    float v = b_ih[t] + b_hh[t];
    b_sum[t] = v;
    bs[t] = v;
    __syncthreads();
    if (t < D) {
        float ig = 1.f / (1.f + __expf(-bs[t]));
        float gg = tanhf(bs[256 + t]);
        float c  = ig * gg;
        float og = 1.f / (1.f + __expf(-bs[384 + t]));
        c1[t] = c;
        h1[t] = og * tanhf(c);
    }
}

// ---------------------------------------------------------------------------
// K3: W1 = w_ih[:, :D] + w_hh; const2 = b_sum + W1 @ h1
// ---------------------------------------------------------------------------
__global__ void init_w1_kernel(const float* __restrict__ w_ih,
                               const float* __restrict__ w_hh,
                               const float* __restrict__ b_sum,
                               const float* __restrict__ h1,
                               float* __restrict__ W1,
                               float* __restrict__ const2) {
    int j = blockIdx.x, k = threadIdx.x;
    float w = w_ih[j * 256 + k] + w_hh[j * 128 + k];
    W1[j * 128 + k] = w;
    __shared__ float red[128];
    red[k] = w * h1[k];
    __syncthreads();
    for (int s = 64; s > 0; s >>= 1) {
        if (k < s) red[k] += red[k + s];
        __syncthreads();
    }
    if (k == 0) const2[j] = b_sum[j] + red[0];
}

// ---------------------------------------------------------------------------
// K4: tiled GEMM: gates[b][j] = base[j] + A1[b]·Wa[j] (+ A2[b]·Wb[j])
// ---------------------------------------------------------------------------
#define BM 64
#define BN 64
#define BK 32
__global__ __launch_bounds__(256) void lstm_gemm_kernel(
    const float* __restrict__ A1, const float* __restrict__ Wa, int wa_stride,
    const float* __restrict__ A2, const float* __restrict__ Wb, int wb_stride,
    const float* __restrict__ base, float* __restrict__ gates, int B_) {
    __shared__ float As[BM][BK + 1];
    __shared__ float Bs[BN][BK + 1];
    int b0 = blockIdx.y * BM;
    int j0 = blockIdx.x * BN;
    int tid = threadIdx.x;
    int tx = tid & 15, ty = tid >> 4;
    float acc[4][4] = {};
    int nphase = A2 ? 2 : 1;
    for (int phase = 0; phase < nphase; phase++) {
        const float* A = phase ? A2 : A1;
        const float* W = phase ? Wb : Wa;
        int ws = phase ? wb_stride : wa_stride;
        for (int k0 = 0; k0 < 128; k0 += BK) {
            __syncthreads();
            for (int i = tid; i < BM * BK; i += 256) {
                int r = i >> 5, cc = i & 31;
                int bb = b0 + r;
                As[r][cc] = (bb < B_) ? A[(size_t)bb * D + k0 + cc] : 0.f;
            }
            for (int i = tid; i < BN * BK; i += 256) {
                int r = i >> 5, cc = i & 31;
                Bs[r][cc] = W[(size_t)(j0 + r) * ws + k0 + cc];
            }
            __syncthreads();
#pragma unroll
            for (int kk = 0; kk < BK; kk++) {
                float av[4], bv[4];
#pragma unroll
                for (int i = 0; i < 4; i++) av[i] = As[ty * 4 + i][kk];
#pragma unroll
                for (int j = 0; j < 4; j++) bv[j] = Bs[tx * 4 + j][kk];
#pragma unroll
                for (int i = 0; i < 4; i++)
#pragma unroll
                    for (int j = 0; j < 4; j++) acc[i][j] += av[i] * bv[j];
            }
        }
    }
    for (int i = 0; i < 4; i++) {
        int bb = b0 + ty * 4 + i;
        if (bb >= B_) continue;
        for (int j = 0; j < 4; j++) {
            int jj = j0 + tx * 4 + j;
            gates[(size_t)bb * 512 + jj] = acc[i][j] + base[jj];
        }
    }
}

// ---------------------------------------------------------------------------
// K5: elementwise LSTM state update from gates
// ---------------------------------------------------------------------------
__global__ void lstm_elem_kernel(const float* __restrict__ gates,
                                 const float* __restrict__ c_prev, int c_bcast,
                                 float* __restrict__ c_out,
                                 float* __restrict__ h_out, int B_) {
    int t = blockIdx.x * 256 + threadIdx.x;
    if (t >= B_ * D) return;
    int b = t >> 7, d = t & (D - 1);
    const float* g = gates + (size_t)b * 512;
    float ig = 1.f / (1.f + __expf(-g[d]));
    float fg = 1.f / (1.f + __expf(-g[128 + d]));
    float gg = tanhf(g[256 + d]);
    float og = 1.f / (1.f + __expf(-g[384 + d]));
    float cp = c_bcast ? c_prev[d] : c_prev[t];
    float c = fg * cp + ig * gg;
    c_out[t] = c;
    h_out[t] = og * tanhf(c);
}

// ---------------------------------------------------------------------------
// K6: attention — R4 structure, unchanged (best passing). Wave-per-graph,
// persistent, gload_lds double-buffer with counted vmcnt, defer-max,
// bit-mixed LDS permutation via pre-swizzled global source.
// ---------------------------------------------------------------------------
__global__ __launch_bounds__(256, 2) void attn_kernel(
    const float* __restrict__ x, const float* __restrict__ q_src, int q_bcast,
    const int* __restrict__ row_ptr, float* __restrict__ out,
    float* __restrict__ final_out, int B_) {

    __shared__ float xs[WPB][2][TILE * D];  // 2 x 8 KB per wave
    __shared__ float qs[WPB][2][256];       // 2 x 1 KB per wave
    __shared__ float wsh[WPB][TILE];

    const int tid  = threadIdx.x;
    const int wave = tid >> 6;
    const int lane = tid & 63;
    const int NW   = gridDim.x * WPB;

    const int p    = lane >> 5;        // staging/acc parity
    const int sc   = lane & 31;        // slot / dim-group id
    const int n    = lane >> 2;        // node id (dot): 0..15
    const int qd   = lane & 3;         // dim quarter (dot)
    const int qdb  = qd << 3;          // dperm(8qd+j) = qdb | ((j+2qd)&7)
    const int qd2  = qd << 1;
    const int dacc = dperm(sc);        // acc slot base
    const int qsrc = dperm_inv(sc);    // q staging source col

    float* xb[2] = {xs[wave][0], xs[wave][1]};
    float* qb[2] = {qs[wave][0], qs[wave][1]};
    float* wsw   = wsh[wave];

    auto issue_tile = [&](int t0, int e_, float* dst) {
#pragma unroll
        for (int j = 0; j < 8; j++) {
            int row = 2 * j + p;                    // in-tile row
            int rg  = t0 + row;
            rg = (rg < e_) ? rg : (e_ - 1);         // clamp (masked by w=0)
            int u = (sc - row) & 31;
            int col = dperm_inv(u);                 // pre-swizzled source col
            gload16(x + ((size_t)rg * D + (col << 2)), dst + j * 256);
        }
    };
    auto issue_q = [&](int bq, float* dst) {
        const float* qp = q_bcast ? q_src : q_src + (size_t)bq * D;
        gload16(qp + (qsrc << 2), dst);             // lanes 32-63 duplicate
    };

    const int S = out ? 1 : 2;                      // stores per finalize
    int b = blockIdx.x * WPB + wave;
    if (b >= B_) return;

    unsigned long long se0 = sload2(row_ptr, b);
    int s = (int)(se0 & 0xffffffffull), e = (int)(se0 >> 32);
    int cur = 0, qc = 0, ps = 0;
    issue_q(b, qb[0]);
    if (s < e) issue_tile(s, e, xb[0]);

    while (1) {
        float m = -1e30f, lsum = 0.f;
        float ax = 0.f, ay = 0.f, az = 0.f, aw = 0.f;
        int sn = 0, en = 0;
        int bn = b + NW;
        int have_next = (bn < B_);

        if (s < e) {
            for (int t0 = s; t0 < e; t0 += TILE) {
                int nt = e - t0; nt = (nt < TILE) ? nt : TILE;
                int just;
                if (t0 + TILE < e) {
                    issue_tile(t0 + TILE, e, xb[cur ^ 1]);
                    just = 8;
                } else if (have_next) {
                    unsigned long long se2 = sload2(row_ptr, bn);
                    sn = (int)(se2 & 0xffffffffull); en = (int)(se2 >> 32);
                    issue_q(bn, qb[qc ^ 1]);
                    just = 1;
                    if (sn < en) { issue_tile(sn, en, xb[cur ^ 1]); just = 9; }
                } else {
                    just = 0;
                }
                wait_vm(just + ps); ps = 0;

                const float4* xw4 = (const float4*)xb[cur];
                const float4* qw4 = (const float4*)qb[qc];

                // dot: 4 lanes/node, 32 dims each; 2 accumulators
                float pd0 = 0.f, pd1 = 0.f;
#pragma unroll
                for (int j = 0; j < 8; j += 2) {
                    int sl0 = ((qdb | ((j + qd2) & 7)) + n) & 31;
                    int sl1 = ((qdb | ((j + 1 + qd2) & 7)) + n) & 31;
                    float4 xv0 = xw4[(n << 5) + sl0];
                    float4 qv0 = qw4[qdb | ((j + qd2) & 7)];
                    float4 xv1 = xw4[(n << 5) + sl1];
                    float4 qv1 = qw4[qdb | ((j + 1 + qd2) & 7)];
                    pd0 += xv0.x * qv0.x + xv0.y * qv0.y + xv0.z * qv0.z + xv0.w * qv0.w;
                    pd1 += xv1.x * qv1.x + xv1.y * qv1.y + xv1.z * qv1.z + xv1.w * qv1.w;
                }
                float pd = pd0 + pd1;
                pd += __shfl_xor(pd, 1);
                pd += __shfl_xor(pd, 2);
                float prod = (n < nt) ? pd : -1e30f;

                // defer-max: fast path skips the max tree + rescale entirely
                if (!__all(prod <= m + THR)) {
                    float tmax = prod;
#pragma unroll
                    for (int mk = 4; mk <= 32; mk <<= 1)
                        tmax = fmaxf(tmax, __shfl_xor(tmax, mk));
                    float m_new = fmaxf(m, tmax);
                    float r = __expf(m - m_new);   // first tile: 0
                    lsum *= r;
                    ax *= r; ay *= r; az *= r; aw *= r;
                    m = m_new;
                }
                float w = __expf(prod - m);        // masked nodes: 0

                float tsum = w;
#pragma unroll
                for (int mk = 4; mk <= 32; mk <<= 1)
                    tsum += __shfl_xor(tsum, mk);
                lsum += tsum;

                if (qd == 0) wsw[n] = w;           // tail rows get w=0

                // accumulate: lane owns dim-group sc, rows of parity p
#pragma unroll
                for (int i = 0; i < 8; i++) {
                    int row = 2 * i + p;
                    float wt = wsw[row];
                    float4 xv = xw4[(row << 5) + ((dacc + row) & 31)];
                    ax += wt * xv.x; ay += wt * xv.y;
                    az += wt * xv.z; aw += wt * xv.w;
                }
                cur ^= 1;
            }
        } else {
            // empty graph: still run the prefetch link of the pipeline
            int just = 0;
            if (have_next) {
                unsigned long long se2 = sload2(row_ptr, bn);
                sn = (int)(se2 & 0xffffffffull); en = (int)(se2 >> 32);
                issue_q(bn, qb[qc ^ 1]);
                just = 1;
                if (sn < en) { issue_tile(sn, en, xb[cur ^ 1]); just = 9; cur ^= 1; }
            }
            wait_vm(just + ps); ps = 0;
        }

        // finalize graph b (q(b) resident in qb[qc])
        ax += __shfl_xor(ax, 32);
        ay += __shfl_xor(ay, 32);
        az += __shfl_xor(az, 32);
        aw += __shfl_xor(aw, 32);
        float inv = 1.f / (lsum + EPS);
        float4 o = {ax * inv, ay * inv, az * inv, aw * inv};
        if (p == 0) {
            if (out) {
                ((float4*)out)[(size_t)b * 32 + sc] = o;
            } else {
                const float4* q4r = (const float4*)qb[qc];
                float4 qv = q4r[dperm(sc)];        // un-permute q
                float4* fo = (float4*)(final_out + (size_t)b * 256);
                fo[sc] = qv;
                fo[32 + sc] = o;
            }
        }
        ps = S;
        if (!have_next) break;
        b = bn; s = sn; e = en; qc ^= 1;
    }
}

// ---------------------------------------------------------------------------
extern "C" void kernel_launch(void* const* d_in, const int* in_sizes, int n_in,
                              void* d_out, int out_size, void* d_ws,
                              size_t ws_size, hipStream_t stream) {
    const float* x    = (const float*)d_in[0];
    const float* w_ih = (const float*)d_in[1];
    const float* w_hh = (const float*)d_in[2];
    const float* b_ih = (const float*)d_in[3];
    const float* b_hh = (const float*)d_in[4];
    const int*   n2g  = (const int*)d_in[5];

    int N_ = in_sizes[0] / D;     // 1,000,000
    int B_ = out_size / (2 * D);  // 10,000

    char* wsb = (char*)d_ws;
    size_t off = 0;
    auto carve = [&](size_t bytes) {
        void* pp = wsb + off;
        off = (off + bytes + 255) & ~(size_t)255;
        return pp;
    };
    int*   row_ptr = (int*)carve((size_t)(B_ + 1) * 4);
    float* b_sum   = (float*)carve(512 * 4);
    float* c1      = (float*)carve(D * 4);
    float* h1      = (float*)carve(D * 4);
    float* const2  = (float*)carve(512 * 4);
    float* W1      = (float*)carve((size_t)512 * D * 4);
    float* hbuf    = (float*)carve((size_t)B_ * D * 4);
    float* cbuf    = (float*)carve((size_t)B_ * D * 4);
    float* outbuf  = (float*)carve((size_t)B_ * D * 4);
    float* gates   = (float*)carve((size_t)B_ * 512 * 4);
    (void)ws_size;

    const float* W2 = w_ih + D;  // rows of w_ih, col offset 128, stride 256

    // --- PROBE (instrumentation): pure-read ceiling measurement. Writes only
    // into `gates`, which the GEMM below fully overwrites. ---
    long long n4 = (long long)N_ * 32;   // x as float4 count
    probe_read_kernel<<<2048, 256, 0, stream>>>((const float4*)x, n4,
                                                (float4*)gates);

    rowptr_kernel<<<(B_ + 1 + 255) / 256, 256, 0, stream>>>(n2g, N_, B_, row_ptr);
    init_consts_kernel<<<1, 512, 0, stream>>>(b_ih, b_hh, b_sum, c1, h1);
    init_w1_kernel<<<512, 128, 0, stream>>>(w_ih, w_hh, b_sum, h1, W1, const2);

    dim3 ggrid(512 / BN, (B_ + BM - 1) / BM);
    int  egrid = (B_ * D + 255) / 256;

    // step 1: query = h1 (broadcast) -> out1
    attn_kernel<<<NBLK, 256, 0, stream>>>(x, h1, 1, row_ptr, outbuf, nullptr, B_);
    // step 2: gates = const2 + out1 @ W2^T ; c_prev = c1 (broadcast)
    lstm_gemm_kernel<<<ggrid, 256, 0, stream>>>(outbuf, W2, 256, nullptr,
                                                nullptr, 0, const2, gates, B_);
    lstm_elem_kernel<<<egrid, 256, 0, stream>>>(gates, c1, 1, cbuf, hbuf, B_);
    attn_kernel<<<NBLK, 256, 0, stream>>>(x, hbuf, 0, row_ptr, outbuf, nullptr, B_);
    // step 3: gates = b_sum + h2 @ W1^T + out2 @ W2^T
    lstm_gemm_kernel<<<ggrid, 256, 0, stream>>>(hbuf, W1, 128, outbuf, W2, 256,
                                                b_sum, gates, B_);
    lstm_elem_kernel<<<egrid, 256, 0, stream>>>(gates, cbuf, 0, cbuf, hbuf, B_);
    // step 3 attention writes final q_star = [h3, out3] directly to d_out
    attn_kernel<<<NBLK, 256, 0, stream>>>(x, hbuf, 0, row_ptr, nullptr,
                                          (float*)d_out, B_);
}

// Round 8
// 526.258 us; speedup vs baseline: 1.7479x; 1.7479x over previous
//
#include <hip/hip_runtime.h>

#define D 128
#define EPS 1e-10f
#define TILE 16
#define WPB 4
#define NBLK 512
#define NBLK_H 768
#define THR 14.0f

typedef _Float16 hf2 __attribute__((ext_vector_type(2)));

__device__ __forceinline__ hf2 as_hf2(float v) { return __builtin_bit_cast(hf2, v); }
__device__ __forceinline__ float as_f32(hf2 v) { return __builtin_bit_cast(float, v); }

__device__ __forceinline__ float fdot2f(hf2 a, hf2 b, float c) {
#if __has_builtin(__builtin_amdgcn_fdot2)
    return __builtin_amdgcn_fdot2(a, b, c, false);
#else
    return (float)a.x * (float)b.x + (float)a.y * (float)b.y + c;
#endif
}

// ---------------------------------------------------------------------------
// async global -> LDS, 16B per lane (dest = base + lane*16, linear)
// ---------------------------------------------------------------------------
__device__ __forceinline__ void gload16(const void* g, void* l) {
    __builtin_amdgcn_global_load_lds(
        (const __attribute__((address_space(1))) void*)g,
        (__attribute__((address_space(3))) void*)l, 16, 0, 0);
}

// scalar load of row_ptr[idx], row_ptr[idx+1] (lgkmcnt path)
__device__ __forceinline__ unsigned long long sload2(const int* rp, int idx) {
    unsigned long long r;
    int off = __builtin_amdgcn_readfirstlane(idx << 2);
    asm volatile("s_load_dwordx2 %0, %1, %2\n\ts_waitcnt lgkmcnt(0)"
                 : "=s"(r) : "s"(rp), "s"(off) : "memory");
    return r;
}

__device__ __forceinline__ void wait_vm(int nn) {
    switch (nn) {
    case 0:  asm volatile("s_waitcnt vmcnt(0)"  ::: "memory"); break;
    case 1:  asm volatile("s_waitcnt vmcnt(1)"  ::: "memory"); break;
    case 2:  asm volatile("s_waitcnt vmcnt(2)"  ::: "memory"); break;
    case 3:  asm volatile("s_waitcnt vmcnt(3)"  ::: "memory"); break;
    case 4:  asm volatile("s_waitcnt vmcnt(4)"  ::: "memory"); break;
    case 5:  asm volatile("s_waitcnt vmcnt(5)"  ::: "memory"); break;
    case 6:  asm volatile("s_waitcnt vmcnt(6)"  ::: "memory"); break;
    case 7:  asm volatile("s_waitcnt vmcnt(7)"  ::: "memory"); break;
    case 8:  asm volatile("s_waitcnt vmcnt(8)"  ::: "memory"); break;
    case 9:  asm volatile("s_waitcnt vmcnt(9)"  ::: "memory"); break;
    case 10: asm volatile("s_waitcnt vmcnt(10)" ::: "memory"); break;
    case 11: asm volatile("s_waitcnt vmcnt(11)" ::: "memory"); break;
    case 12: asm volatile("s_waitcnt vmcnt(12)" ::: "memory"); break;
    case 13: asm volatile("s_waitcnt vmcnt(13)" ::: "memory"); break;
    case 14: asm volatile("s_waitcnt vmcnt(14)" ::: "memory"); break;
    default: asm volatile("s_waitcnt vmcnt(0)"  ::: "memory"); break;
    }
}

// bit-mixed dim-group -> slot permutation (f32 kernel, 4-float groups)
__device__ __forceinline__ int dperm(int d) {
    return (d & 24) | ((d + 2 * (d >> 3)) & 7);
}
__device__ __forceinline__ int dperm_inv(int u) {
    int q = u >> 3;
    return (q << 3) | ((u - 2 * q) & 7);
}

// ---------------------------------------------------------------------------
// K1: row_ptr via binary search (node2graph sorted)
// ---------------------------------------------------------------------------
__global__ void rowptr_kernel(const int* __restrict__ n2g, int N_, int B_,
                              int* __restrict__ row_ptr) {
    int b = blockIdx.x * 256 + threadIdx.x;
    if (b > B_) return;
    if (b == B_) { row_ptr[b] = N_; return; }
    int lo = 0, hi = N_;
    while (lo < hi) {
        int mid = (lo + hi) >> 1;
        if (n2g[mid] < b) lo = mid + 1; else hi = mid;
    }
    row_ptr[b] = lo;
}

// ---------------------------------------------------------------------------
// K2: b_sum = b_ih + b_hh; step-1 constants h1, c1
// ---------------------------------------------------------------------------
__global__ void init_consts_kernel(const float* __restrict__ b_ih,
                                   const float* __restrict__ b_hh,
                                   float* __restrict__ b_sum,
                                   float* __restrict__ c1,
                                   float* __restrict__ h1) {
    int t = threadIdx.x;  // 512 threads, 1 block
    __shared__ float bs[512];
    float v = b_ih[t] + b_hh[t];
    b_sum[t] = v;
    bs[t] = v;
    __syncthreads();
    if (t < D) {
        float ig = 1.f / (1.f + __expf(-bs[t]));
        float gg = tanhf(bs[256 + t]);
        float c  = ig * gg;
        float og = 1.f / (1.f + __expf(-bs[384 + t]));
        c1[t] = c;
        h1[t] = og * tanhf(c);
    }
}

// ---------------------------------------------------------------------------
// K3: W1 = w_ih[:, :D] + w_hh; const2 = b_sum + W1 @ h1
// ---------------------------------------------------------------------------
__global__ void init_w1_kernel(const float* __restrict__ w_ih,
                               const float* __restrict__ w_hh,
                               const float* __restrict__ b_sum,
                               const float* __restrict__ h1,
                               float* __restrict__ W1,
                               float* __restrict__ const2) {
    int j = blockIdx.x, k = threadIdx.x;
    float w = w_ih[j * 256 + k] + w_hh[j * 128 + k];
    W1[j * 128 + k] = w;
    __shared__ float red[128];
    red[k] = w * h1[k];
    __syncthreads();
    for (int s = 64; s > 0; s >>= 1) {
        if (k < s) red[k] += red[k + s];
        __syncthreads();
    }
    if (k == 0) const2[j] = b_sum[j] + red[0];
}

// ---------------------------------------------------------------------------
// K4: tiled GEMM: gates[b][j] = base[j] + A1[b]·Wa[j] (+ A2[b]·Wb[j])
// ---------------------------------------------------------------------------
#define BM 64
#define BN 64
#define BK 32
__global__ __launch_bounds__(256) void lstm_gemm_kernel(
    const float* __restrict__ A1, const float* __restrict__ Wa, int wa_stride,
    const float* __restrict__ A2, const float* __restrict__ Wb, int wb_stride,
    const float* __restrict__ base, float* __restrict__ gates, int B_) {
    __shared__ float As[BM][BK + 1];
    __shared__ float Bs[BN][BK + 1];
    int b0 = blockIdx.y * BM;
    int j0 = blockIdx.x * BN;
    int tid = threadIdx.x;
    int tx = tid & 15, ty = tid >> 4;
    float acc[4][4] = {};
    int nphase = A2 ? 2 : 1;
    for (int phase = 0; phase < nphase; phase++) {
        const float* A = phase ? A2 : A1;
        const float* W = phase ? Wb : Wa;
        int ws = phase ? wb_stride : wa_stride;
        for (int k0 = 0; k0 < 128; k0 += BK) {
            __syncthreads();
            for (int i = tid; i < BM * BK; i += 256) {
                int r = i >> 5, cc = i & 31;
                int bb = b0 + r;
                As[r][cc] = (bb < B_) ? A[(size_t)bb * D + k0 + cc] : 0.f;
            }
            for (int i = tid; i < BN * BK; i += 256) {
                int r = i >> 5, cc = i & 31;
                Bs[r][cc] = W[(size_t)(j0 + r) * ws + k0 + cc];
            }
            __syncthreads();
#pragma unroll
            for (int kk = 0; kk < BK; kk++) {
                float av[4], bv[4];
#pragma unroll
                for (int i = 0; i < 4; i++) av[i] = As[ty * 4 + i][kk];
#pragma unroll
                for (int j = 0; j < 4; j++) bv[j] = Bs[tx * 4 + j][kk];
#pragma unroll
                for (int i = 0; i < 4; i++)
#pragma unroll
                    for (int j = 0; j < 4; j++) acc[i][j] += av[i] * bv[j];
            }
        }
    }
    for (int i = 0; i < 4; i++) {
        int bb = b0 + ty * 4 + i;
        if (bb >= B_) continue;
        for (int j = 0; j < 4; j++) {
            int jj = j0 + tx * 4 + j;
            gates[(size_t)bb * 512 + jj] = acc[i][j] + base[jj];
        }
    }
}

// ---------------------------------------------------------------------------
// K5: elementwise LSTM state update from gates
// ---------------------------------------------------------------------------
__global__ void lstm_elem_kernel(const float* __restrict__ gates,
                                 const float* __restrict__ c_prev, int c_bcast,
                                 float* __restrict__ c_out,
                                 float* __restrict__ h_out, int B_) {
    int t = blockIdx.x * 256 + threadIdx.x;
    if (t >= B_ * D) return;
    int b = t >> 7, d = t & (D - 1);
    const float* g = gates + (size_t)b * 512;
    float ig = 1.f / (1.f + __expf(-g[d]));
    float fg = 1.f / (1.f + __expf(-g[128 + d]));
    float gg = tanhf(g[256 + d]);
    float og = 1.f / (1.f + __expf(-g[384 + d]));
    float cp = c_bcast ? c_prev[d] : c_prev[t];
    float c = fg * cp + ig * gg;
    c_out[t] = c;
    h_out[t] = og * tanhf(c);
}

// ---------------------------------------------------------------------------
// K6: f32 attention (R4 structure) + optional fused f32->fp16 emission of x.
// When xh != nullptr, each staged tile is also written out row-major as fp16
// (4 extra stores/lane/tile, accounted in the counted-vmcnt invariant).
// ---------------------------------------------------------------------------
__global__ __launch_bounds__(256, 2) void attn_kernel(
    const float* __restrict__ x, const float* __restrict__ q_src, int q_bcast,
    const int* __restrict__ row_ptr, float* __restrict__ out,
    float* __restrict__ final_out, int B_, _Float16* __restrict__ xh) {

    __shared__ float xs[WPB][2][TILE * D];  // 2 x 8 KB per wave
    __shared__ float qs[WPB][2][256];       // 2 x 1 KB per wave
    __shared__ float wsh[WPB][TILE];

    const int tid  = threadIdx.x;
    const int wave = tid >> 6;
    const int lane = tid & 63;
    const int NW   = gridDim.x * WPB;

    const int p    = lane >> 5;        // staging/acc parity
    const int sc   = lane & 31;        // slot / dim-group id
    const int n    = lane >> 2;        // node id (dot): 0..15
    const int qd   = lane & 3;         // dim quarter (dot)
    const int qdb  = qd << 3;
    const int qd2  = qd << 1;
    const int dacc = dperm(sc);
    const int qsrc = dperm_inv(sc);

    float* xb[2] = {xs[wave][0], xs[wave][1]};
    float* qb[2] = {qs[wave][0], qs[wave][1]};
    float* wsw   = wsh[wave];

    auto issue_tile = [&](int t0, int e_, float* dst) {
#pragma unroll
        for (int j = 0; j < 8; j++) {
            int row = 2 * j + p;
            int rg  = t0 + row;
            rg = (rg < e_) ? rg : (e_ - 1);
            int u = (sc - row) & 31;
            int col = dperm_inv(u);
            gload16(x + ((size_t)rg * D + (col << 2)), dst + j * 256);
        }
    };
    auto issue_q = [&](int bq, float* dst) {
        const float* qp = q_bcast ? q_src : q_src + (size_t)bq * D;
        gload16(qp + (qsrc << 2), dst);
    };

    const int S = out ? 1 : 2;
    int b = blockIdx.x * WPB + wave;
    if (b >= B_) return;

    unsigned long long se0 = sload2(row_ptr, b);
    int s = (int)(se0 & 0xffffffffull), e = (int)(se0 >> 32);
    int cur = 0, qc = 0, ps = 0;
    issue_q(b, qb[0]);
    if (s < e) issue_tile(s, e, xb[0]);

    while (1) {
        float m = -1e30f, lsum = 0.f;
        float ax = 0.f, ay = 0.f, az = 0.f, aw = 0.f;
        int sn = 0, en = 0;
        int bn = b + NW;
        int have_next = (bn < B_);

        if (s < e) {
            for (int t0 = s; t0 < e; t0 += TILE) {
                int nt = e - t0; nt = (nt < TILE) ? nt : TILE;
                int just;
                if (t0 + TILE < e) {
                    issue_tile(t0 + TILE, e, xb[cur ^ 1]);
                    just = 8;
                } else if (have_next) {
                    unsigned long long se2 = sload2(row_ptr, bn);
                    sn = (int)(se2 & 0xffffffffull); en = (int)(se2 >> 32);
                    issue_q(bn, qb[qc ^ 1]);
                    just = 1;
                    if (sn < en) { issue_tile(sn, en, xb[cur ^ 1]); just = 9; }
                } else {
                    just = 0;
                }
                wait_vm(just + ps); ps = 0;

                const float4* xw4 = (const float4*)xb[cur];
                const float4* qw4 = (const float4*)qb[qc];

                // fused convert: emit this tile as fp16, row-major
                if (xh) {
                    int row = n, qq = qd;        // reuse decomp: 16x4 lanes
                    float dw[16];
#pragma unroll
                    for (int i = 0; i < 8; i++) {
                        int sl = ((qq * 8 + ((i + 2 * qq) & 7)) + row) & 31;
                        float4 f = xw4[(row << 5) + sl];
                        hf2 h0 = {(_Float16)f.x, (_Float16)f.y};
                        hf2 h1 = {(_Float16)f.z, (_Float16)f.w};
                        dw[2 * i]     = as_f32(h0);
                        dw[2 * i + 1] = as_f32(h1);
                    }
                    int rowg = t0 + row;
                    rowg = (rowg < e) ? rowg : (e - 1);   // idempotent clamp
                    float4* xo = (float4*)((char*)xh +
                                 ((size_t)rowg * 256 + (qq << 6)));
                    xo[0] = make_float4(dw[0], dw[1], dw[2], dw[3]);
                    xo[1] = make_float4(dw[4], dw[5], dw[6], dw[7]);
                    xo[2] = make_float4(dw[8], dw[9], dw[10], dw[11]);
                    xo[3] = make_float4(dw[12], dw[13], dw[14], dw[15]);
                    ps += 4;
                }

                // dot: 4 lanes/node, 32 dims each; 2 accumulators
                float pd0 = 0.f, pd1 = 0.f;
#pragma unroll
                for (int j = 0; j < 8; j += 2) {
                    int sl0 = ((qdb | ((j + qd2) & 7)) + n) & 31;
                    int sl1 = ((qdb | ((j + 1 + qd2) & 7)) + n) & 31;
                    float4 xv0 = xw4[(n << 5) + sl0];
                    float4 qv0 = qw4[qdb | ((j + qd2) & 7)];
                    float4 xv1 = xw4[(n << 5) + sl1];
                    float4 qv1 = qw4[qdb | ((j + 1 + qd2) & 7)];
                    pd0 += xv0.x * qv0.x + xv0.y * qv0.y + xv0.z * qv0.z + xv0.w * qv0.w;
                    pd1 += xv1.x * qv1.x + xv1.y * qv1.y + xv1.z * qv1.z + xv1.w * qv1.w;
                }
                float pd = pd0 + pd1;
                pd += __shfl_xor(pd, 1);
                pd += __shfl_xor(pd, 2);
                float prod = (n < nt) ? pd : -1e30f;

                if (!__all(prod <= m + THR)) {
                    float tmax = prod;
#pragma unroll
                    for (int mk = 4; mk <= 32; mk <<= 1)
                        tmax = fmaxf(tmax, __shfl_xor(tmax, mk));
                    float m_new = fmaxf(m, tmax);
                    float r = __expf(m - m_new);
                    lsum *= r;
                    ax *= r; ay *= r; az *= r; aw *= r;
                    m = m_new;
                }
                float w = __expf(prod - m);

                float tsum = w;
#pragma unroll
                for (int mk = 4; mk <= 32; mk <<= 1)
                    tsum += __shfl_xor(tsum, mk);
                lsum += tsum;

                if (qd == 0) wsw[n] = w;

#pragma unroll
                for (int i = 0; i < 8; i++) {
                    int row = 2 * i + p;
                    float wt = wsw[row];
                    float4 xv = xw4[(row << 5) + ((dacc + row) & 31)];
                    ax += wt * xv.x; ay += wt * xv.y;
                    az += wt * xv.z; aw += wt * xv.w;
                }
                cur ^= 1;
            }
        } else {
            int just = 0;
            if (have_next) {
                unsigned long long se2 = sload2(row_ptr, bn);
                sn = (int)(se2 & 0xffffffffull); en = (int)(se2 >> 32);
                issue_q(bn, qb[qc ^ 1]);
                just = 1;
                if (sn < en) { issue_tile(sn, en, xb[cur ^ 1]); just = 9; cur ^= 1; }
            }
            wait_vm(just + ps); ps = 0;
        }

        // finalize graph b
        ax += __shfl_xor(ax, 32);
        ay += __shfl_xor(ay, 32);
        az += __shfl_xor(az, 32);
        aw += __shfl_xor(aw, 32);
        float inv = 1.f / (lsum + EPS);
        float4 o = {ax * inv, ay * inv, az * inv, aw * inv};
        if (p == 0) {
            if (out) {
                ((float4*)out)[(size_t)b * 32 + sc] = o;
            } else {
                const float4* q4r = (const float4*)qb[qc];
                float4 qv = q4r[dperm(sc)];
                float4* fo = (float4*)(final_out + (size_t)b * 256);
                fo[sc] = qv;
                fo[32 + sc] = o;
            }
        }
        ps += S;
        if (!have_next) break;
        b = bn; s = sn; e = en; qc ^= 1;
    }
}

// ---------------------------------------------------------------------------
// K7: fp16 attention (passes 2-3). R4 skeleton on half data: 4 KB tiles
// (4 gloads), 16B-group rotation layout, v_dot2_f32_f16 dot, f32 accum.
// q staged f32 via gload_lds (1 vmem op), converted to half2 once per graph.
// ---------------------------------------------------------------------------
__global__ __launch_bounds__(256, 2) void attn_h_kernel(
    const _Float16* __restrict__ xh, const float* __restrict__ q_src,
    const int* __restrict__ row_ptr, float* __restrict__ out,
    float* __restrict__ final_out, int B_) {

    __shared__ float xs[WPB][2][TILE * 64];  // 4 KB per buffer (half data)
    __shared__ float qf[WPB][2][256];        // staged q f32 (1 KB incl dup)
    __shared__ float qh[WPB][64];            // q as half2 (256 B)
    __shared__ float wsh[WPB][TILE];

    const int tid  = threadIdx.x;
    const int wave = tid >> 6;
    const int lane = tid & 63;
    const int NW   = gridDim.x * WPB;

    const int n  = lane >> 2;    // dot: node 0..15
    const int qd = lane & 3;     // dot: dim quarter
    const int g  = lane & 15;    // acc: 16B group (8 dims)
    const int pp = lane >> 4;    // acc: row phase 0..3

    float* xb[2] = {xs[wave][0], xs[wave][1]};
    float* qb[2] = {qf[wave][0], qf[wave][1]};
    float* qhw   = qh[wave];
    float* wsw   = wsh[wave];

    auto issue_tile = [&](int t0, int e_, float* dst) {
#pragma unroll
        for (int j = 0; j < 4; j++) {
            int idx = (j << 6) + lane;           // 0..255 slots
            int row = idx >> 4, s16 = idx & 15;
            int rg = t0 + row;
            rg = (rg < e_) ? rg : (e_ - 1);
            int gg = (s16 - row) & 15;           // pre-swizzled source group
            gload16((const char*)xh + ((size_t)rg << 8) + (gg << 4),
                    dst + (j << 8));
        }
    };
    auto issue_q = [&](int bq, float* dst) {
        gload16(q_src + ((size_t)bq << 7) + ((lane & 31) << 2), dst);
    };

    const int S = out ? 2 : 4;
    int b = blockIdx.x * WPB + wave;
    if (b >= B_) return;

    unsigned long long se0 = sload2(row_ptr, b);
    int s = (int)(se0 & 0xffffffffull), e = (int)(se0 >> 32);
    int cur = 0, qc = 0, ps = 0;
    issue_q(b, qb[0]);
    if (s < e) issue_tile(s, e, xb[0]);

    while (1) {
        float m = -1e30f, lsum = 0.f;
        float a[8] = {0.f, 0.f, 0.f, 0.f, 0.f, 0.f, 0.f, 0.f};
        int sn = 0, en = 0;
        int bn = b + NW;
        int have_next = (bn < B_);

        if (s < e) {
            for (int t0 = s; t0 < e; t0 += TILE) {
                int nt = e - t0; nt = (nt < TILE) ? nt : TILE;
                int just;
                if (t0 + TILE < e) {
                    issue_tile(t0 + TILE, e, xb[cur ^ 1]);
                    just = 4;
                } else if (have_next) {
                    unsigned long long se2 = sload2(row_ptr, bn);
                    sn = (int)(se2 & 0xffffffffull); en = (int)(se2 >> 32);
                    issue_q(bn, qb[qc ^ 1]);
                    just = 1;
                    if (sn < en) { issue_tile(sn, en, xb[cur ^ 1]); just = 5; }
                } else {
                    just = 0;
                }
                wait_vm(just + ps); ps = 0;

                if (t0 == s) {  // convert this graph's q: f32 -> half2
                    float2 f2 = ((const float2*)qb[qc])[lane];
                    hf2 hq = {(_Float16)f2.x, (_Float16)f2.y};
                    qhw[lane] = as_f32(hq);
                }

                const float4* xw4 = (const float4*)xb[cur];
                const float4* qh4 = (const float4*)qhw;

                // dot: 4 lanes/node, 32 dims each via fdot2
                float pd0 = 0.f, pd1 = 0.f;
#pragma unroll
                for (int j = 0; j < 4; j++) {
                    int gg = (qd << 2) + j;
                    float4 xv = xw4[(n << 4) + ((gg + n) & 15)];
                    float4 qv = qh4[gg];
                    pd0 = fdot2f(as_hf2(xv.x), as_hf2(qv.x), pd0);
                    pd1 = fdot2f(as_hf2(xv.y), as_hf2(qv.y), pd1);
                    pd0 = fdot2f(as_hf2(xv.z), as_hf2(qv.z), pd0);
                    pd1 = fdot2f(as_hf2(xv.w), as_hf2(qv.w), pd1);
                }
                float pd = pd0 + pd1;
                pd += __shfl_xor(pd, 1);
                pd += __shfl_xor(pd, 2);
                float prod = (n < nt) ? pd : -1e30f;

                if (!__all(prod <= m + THR)) {
                    float tmax = prod;
#pragma unroll
                    for (int mk = 4; mk <= 32; mk <<= 1)
                        tmax = fmaxf(tmax, __shfl_xor(tmax, mk));
                    float m_new = fmaxf(m, tmax);
                    float r = __expf(m - m_new);
                    lsum *= r;
#pragma unroll
                    for (int k = 0; k < 8; k++) a[k] *= r;
                    m = m_new;
                }
                float w = __expf(prod - m);

                float tsum = w;
#pragma unroll
                for (int mk = 4; mk <= 32; mk <<= 1)
                    tsum += __shfl_xor(tsum, mk);
                lsum += tsum;

                if (qd == 0) wsw[n] = w;

                // accumulate: lane owns group g (8 dims), rows 4i+pp
#pragma unroll
                for (int i = 0; i < 4; i++) {
                    int ro = (i << 2) + pp;
                    float wt = wsw[ro];
                    float4 xv = xw4[(ro << 4) + ((g + ro) & 15)];
                    hf2 h0 = as_hf2(xv.x), h1 = as_hf2(xv.y);
                    hf2 h2 = as_hf2(xv.z), h3 = as_hf2(xv.w);
                    a[0] += wt * (float)h0.x; a[1] += wt * (float)h0.y;
                    a[2] += wt * (float)h1.x; a[3] += wt * (float)h1.y;
                    a[4] += wt * (float)h2.x; a[5] += wt * (float)h2.y;
                    a[6] += wt * (float)h3.x; a[7] += wt * (float)h3.y;
                }
                cur ^= 1;
            }
        } else {
            int just = 0;
            if (have_next) {
                unsigned long long se2 = sload2(row_ptr, bn);
                sn = (int)(se2 & 0xffffffffull); en = (int)(se2 >> 32);
                issue_q(bn, qb[qc ^ 1]);
                just = 1;
                if (sn < en) { issue_tile(sn, en, xb[cur ^ 1]); just = 5; cur ^= 1; }
            }
            wait_vm(just + ps); ps = 0;
        }

        // finalize graph b: reduce over pp (4 lanes per group)
#pragma unroll
        for (int k = 0; k < 8; k++) {
            a[k] += __shfl_xor(a[k], 16);
            a[k] += __shfl_xor(a[k], 32);
        }
        float inv = 1.f / (lsum + EPS);
        if (pp == 0) {
            float4 o0 = {a[0] * inv, a[1] * inv, a[2] * inv, a[3] * inv};
            float4 o1 = {a[4] * inv, a[5] * inv, a[6] * inv, a[7] * inv};
            if (out) {
                float4* op = (float4*)(out + (size_t)b * D + (g << 3));
                op[0] = o0; op[1] = o1;
            } else {
                const float4* q4r = (const float4*)qb[qc];
                float4 q0 = q4r[g * 2], q1 = q4r[g * 2 + 1];
                float4* fo = (float4*)(final_out + (size_t)b * 256 + (g << 3));
                fo[0] = q0; fo[1] = q1;
                float4* fo2 = (float4*)(final_out + (size_t)b * 256 + D + (g << 3));
                fo2[0] = o0; fo2[1] = o1;
            }
        }
        ps += S;
        if (!have_next) break;
        b = bn; s = sn; e = en; qc ^= 1;
    }
}

// ---------------------------------------------------------------------------
extern "C" void kernel_launch(void* const* d_in, const int* in_sizes, int n_in,
                              void* d_out, int out_size, void* d_ws,
                              size_t ws_size, hipStream_t stream) {
    const float* x    = (const float*)d_in[0];
    const float* w_ih = (const float*)d_in[1];
    const float* w_hh = (const float*)d_in[2];
    const float* b_ih = (const float*)d_in[3];
    const float* b_hh = (const float*)d_in[4];
    const int*   n2g  = (const int*)d_in[5];

    int N_ = in_sizes[0] / D;     // 1,000,000
    int B_ = out_size / (2 * D);  // 10,000

    char* wsb = (char*)d_ws;
    size_t off = 0;
    auto carve = [&](size_t bytes) {
        void* pp = wsb + off;
        off = (off + bytes + 255) & ~(size_t)255;
        return pp;
    };
    int*   row_ptr = (int*)carve((size_t)(B_ + 1) * 4);
    float* b_sum   = (float*)carve(512 * 4);
    float* c1      = (float*)carve(D * 4);
    float* h1      = (float*)carve(D * 4);
    float* const2  = (float*)carve(512 * 4);
    float* W1      = (float*)carve((size_t)512 * D * 4);
    float* hbuf    = (float*)carve((size_t)B_ * D * 4);
    float* cbuf    = (float*)carve((size_t)B_ * D * 4);
    float* outbuf  = (float*)carve((size_t)B_ * D * 4);
    float* gates   = (float*)carve((size_t)B_ * 512 * 4);
    _Float16* xh   = (_Float16*)carve((size_t)N_ * D * 2);   // 256 MB
    bool use_half = (off <= ws_size);

    const float* W2 = w_ih + D;  // rows of w_ih, col offset 128, stride 256

    rowptr_kernel<<<(B_ + 1 + 255) / 256, 256, 0, stream>>>(n2g, N_, B_, row_ptr);
    init_consts_kernel<<<1, 512, 0, stream>>>(b_ih, b_hh, b_sum, c1, h1);
    init_w1_kernel<<<512, 128, 0, stream>>>(w_ih, w_hh, b_sum, h1, W1, const2);

    dim3 ggrid(512 / BN, (B_ + BM - 1) / BM);
    int  egrid = (B_ * D + 255) / 256;

    if (use_half) {
        // pass 1 (f32, fused fp16 emission)
        attn_kernel<<<NBLK, 256, 0, stream>>>(x, h1, 1, row_ptr, outbuf,
                                              nullptr, B_, xh);
        lstm_gemm_kernel<<<ggrid, 256, 0, stream>>>(outbuf, W2, 256, nullptr,
                                                    nullptr, 0, const2, gates, B_);
        lstm_elem_kernel<<<egrid, 256, 0, stream>>>(gates, c1, 1, cbuf, hbuf, B_);
        // pass 2 (fp16)
        attn_h_kernel<<<NBLK_H, 256, 0, stream>>>(xh, hbuf, row_ptr, outbuf,
                                                  nullptr, B_);
        lstm_gemm_kernel<<<ggrid, 256, 0, stream>>>(hbuf, W1, 128, outbuf, W2, 256,
                                                    b_sum, gates, B_);
        lstm_elem_kernel<<<egrid, 256, 0, stream>>>(gates, cbuf, 0, cbuf, hbuf, B_);
        // pass 3 (fp16, writes q_star)
        attn_h_kernel<<<NBLK_H, 256, 0, stream>>>(xh, hbuf, row_ptr, nullptr,
                                                  (float*)d_out, B_);
    } else {
        // fallback: R4 sequence (all-f32), no conversion
        attn_kernel<<<NBLK, 256, 0, stream>>>(x, h1, 1, row_ptr, outbuf,
                                              nullptr, B_, nullptr);
        lstm_gemm_kernel<<<ggrid, 256, 0, stream>>>(outbuf, W2, 256, nullptr,
                                                    nullptr, 0, const2, gates, B_);
        lstm_elem_kernel<<<egrid, 256, 0, stream>>>(gates, c1, 1, cbuf, hbuf, B_);
        attn_kernel<<<NBLK, 256, 0, stream>>>(x, hbuf, 0, row_ptr, outbuf,
                                              nullptr, B_, nullptr);
        lstm_gemm_kernel<<<ggrid, 256, 0, stream>>>(hbuf, W1, 128, outbuf, W2, 256,
                                                    b_sum, gates, B_);
        lstm_elem_kernel<<<egrid, 256, 0, stream>>>(gates, cbuf, 0, cbuf, hbuf, B_);
        attn_kernel<<<NBLK, 256, 0, stream>>>(x, hbuf, 0, row_ptr, nullptr,
                                              (float*)d_out, B_, nullptr);
    }
}

// Round 9
// 440.820 us; speedup vs baseline: 2.0867x; 1.1938x over previous
//
#include <hip/hip_runtime.h>

#define D 128
#define EPS 1e-10f
#define TILE 16
#define TILE_H 32
#define WPB 4
#define NBLK 512
#define NBLK_H 768
#define THR 14.0f

typedef _Float16 hf2 __attribute__((ext_vector_type(2)));

__device__ __forceinline__ hf2 as_hf2(float v) { return __builtin_bit_cast(hf2, v); }
__device__ __forceinline__ float as_f32(hf2 v) { return __builtin_bit_cast(float, v); }

__device__ __forceinline__ float fdot2f(hf2 a, hf2 b, float c) {
#if __has_builtin(__builtin_amdgcn_fdot2)
    return __builtin_amdgcn_fdot2(a, b, c, false);
#else
    return (float)a.x * (float)b.x + (float)a.y * (float)b.y + c;
#endif
}

// ---------------------------------------------------------------------------
// async global -> LDS, 16B per lane (dest = base + lane*16, linear)
// ---------------------------------------------------------------------------
__device__ __forceinline__ void gload16(const void* g, void* l) {
    __builtin_amdgcn_global_load_lds(
        (const __attribute__((address_space(1))) void*)g,
        (__attribute__((address_space(3))) void*)l, 16, 0, 0);
}

// scalar load of row_ptr[idx], row_ptr[idx+1] (lgkmcnt path)
__device__ __forceinline__ unsigned long long sload2(const int* rp, int idx) {
    unsigned long long r;
    int off = __builtin_amdgcn_readfirstlane(idx << 2);
    asm volatile("s_load_dwordx2 %0, %1, %2\n\ts_waitcnt lgkmcnt(0)"
                 : "=s"(r) : "s"(rp), "s"(off) : "memory");
    return r;
}

__device__ __forceinline__ void wait_vm(int nn) {
    switch (nn) {
    case 0:  asm volatile("s_waitcnt vmcnt(0)"  ::: "memory"); break;
    case 1:  asm volatile("s_waitcnt vmcnt(1)"  ::: "memory"); break;
    case 2:  asm volatile("s_waitcnt vmcnt(2)"  ::: "memory"); break;
    case 3:  asm volatile("s_waitcnt vmcnt(3)"  ::: "memory"); break;
    case 4:  asm volatile("s_waitcnt vmcnt(4)"  ::: "memory"); break;
    case 5:  asm volatile("s_waitcnt vmcnt(5)"  ::: "memory"); break;
    case 6:  asm volatile("s_waitcnt vmcnt(6)"  ::: "memory"); break;
    case 7:  asm volatile("s_waitcnt vmcnt(7)"  ::: "memory"); break;
    case 8:  asm volatile("s_waitcnt vmcnt(8)"  ::: "memory"); break;
    case 9:  asm volatile("s_waitcnt vmcnt(9)"  ::: "memory"); break;
    case 10: asm volatile("s_waitcnt vmcnt(10)" ::: "memory"); break;
    case 11: asm volatile("s_waitcnt vmcnt(11)" ::: "memory"); break;
    case 12: asm volatile("s_waitcnt vmcnt(12)" ::: "memory"); break;
    case 13: asm volatile("s_waitcnt vmcnt(13)" ::: "memory"); break;
    case 14: asm volatile("s_waitcnt vmcnt(14)" ::: "memory"); break;
    case 15: asm volatile("s_waitcnt vmcnt(15)" ::: "memory"); break;
    case 16: asm volatile("s_waitcnt vmcnt(16)" ::: "memory"); break;
    case 17: asm volatile("s_waitcnt vmcnt(17)" ::: "memory"); break;
    case 18: asm volatile("s_waitcnt vmcnt(18)" ::: "memory"); break;
    case 19: asm volatile("s_waitcnt vmcnt(19)" ::: "memory"); break;
    case 20: asm volatile("s_waitcnt vmcnt(20)" ::: "memory"); break;
    default: asm volatile("s_waitcnt vmcnt(0)"  ::: "memory"); break;
    }
}

// bit-mixed dim-group -> slot permutation (f32 kernel, 4-float groups)
__device__ __forceinline__ int dperm(int d) {
    return (d & 24) | ((d + 2 * (d >> 3)) & 7);
}
__device__ __forceinline__ int dperm_inv(int u) {
    int q = u >> 3;
    return (q << 3) | ((u - 2 * q) & 7);
}

// ---------------------------------------------------------------------------
// K1: row_ptr via binary search (node2graph sorted)
// ---------------------------------------------------------------------------
__global__ void rowptr_kernel(const int* __restrict__ n2g, int N_, int B_,
                              int* __restrict__ row_ptr) {
    int b = blockIdx.x * 256 + threadIdx.x;
    if (b > B_) return;
    if (b == B_) { row_ptr[b] = N_; return; }
    int lo = 0, hi = N_;
    while (lo < hi) {
        int mid = (lo + hi) >> 1;
        if (n2g[mid] < b) lo = mid + 1; else hi = mid;
    }
    row_ptr[b] = lo;
}

// ---------------------------------------------------------------------------
// K2: b_sum = b_ih + b_hh; step-1 constants h1, c1
// ---------------------------------------------------------------------------
__global__ void init_consts_kernel(const float* __restrict__ b_ih,
                                   const float* __restrict__ b_hh,
                                   float* __restrict__ b_sum,
                                   float* __restrict__ c1,
                                   float* __restrict__ h1) {
    int t = threadIdx.x;  // 512 threads, 1 block
    __shared__ float bs[512];
    float v = b_ih[t] + b_hh[t];
    b_sum[t] = v;
    bs[t] = v;
    __syncthreads();
    if (t < D) {
        float ig = 1.f / (1.f + __expf(-bs[t]));
        float gg = tanhf(bs[256 + t]);
        float c  = ig * gg;
        float og = 1.f / (1.f + __expf(-bs[384 + t]));
        c1[t] = c;
        h1[t] = og * tanhf(c);
    }
}

// ---------------------------------------------------------------------------
// K3: W1 = w_ih[:, :D] + w_hh; const2 = b_sum + W1 @ h1
// ---------------------------------------------------------------------------
__global__ void init_w1_kernel(const float* __restrict__ w_ih,
                               const float* __restrict__ w_hh,
                               const float* __restrict__ b_sum,
                               const float* __restrict__ h1,
                               float* __restrict__ W1,
                               float* __restrict__ const2) {
    int j = blockIdx.x, k = threadIdx.x;
    float w = w_ih[j * 256 + k] + w_hh[j * 128 + k];
    W1[j * 128 + k] = w;
    __shared__ float red[128];
    red[k] = w * h1[k];
    __syncthreads();
    for (int s = 64; s > 0; s >>= 1) {
        if (k < s) red[k] += red[k + s];
        __syncthreads();
    }
    if (k == 0) const2[j] = b_sum[j] + red[0];
}

// ---------------------------------------------------------------------------
// K4: tiled GEMM with packed-fp16 v_dot2_f32_f16 inner loop (f32 accumulate).
// gates[b][j] = base[j] + A1[b]·Wa[j] (+ A2[b]·Wb[j])
// ---------------------------------------------------------------------------
#define BM 64
#define BN 64
#define BK 32
__global__ __launch_bounds__(256) void lstm_gemm_kernel(
    const float* __restrict__ A1, const float* __restrict__ Wa, int wa_stride,
    const float* __restrict__ A2, const float* __restrict__ Wb, int wb_stride,
    const float* __restrict__ base, float* __restrict__ gates, int B_) {
    __shared__ float As[BM][BK / 2 + 1];   // packed half2
    __shared__ float Bs[BN][BK / 2 + 1];
    int b0 = blockIdx.y * BM;
    int j0 = blockIdx.x * BN;
    int tid = threadIdx.x;
    int tx = tid & 15, ty = tid >> 4;
    float acc[4][4] = {};
    int nphase = A2 ? 2 : 1;
    for (int phase = 0; phase < nphase; phase++) {
        const float* A = phase ? A2 : A1;
        const float* W = phase ? Wb : Wa;
        int ws = phase ? wb_stride : wa_stride;
        for (int k0 = 0; k0 < 128; k0 += BK) {
            __syncthreads();
            for (int i = tid; i < BM * (BK / 2); i += 256) {
                int r = i >> 4, cc = i & 15;
                int bb = b0 + r;
                float2 f2 = (bb < B_)
                    ? *(const float2*)&A[(size_t)bb * D + k0 + 2 * cc]
                    : make_float2(0.f, 0.f);
                hf2 h = {(_Float16)f2.x, (_Float16)f2.y};
                As[r][cc] = as_f32(h);
            }
            for (int i = tid; i < BN * (BK / 2); i += 256) {
                int r = i >> 4, cc = i & 15;
                float2 f2 = *(const float2*)&W[(size_t)(j0 + r) * ws + k0 + 2 * cc];
                hf2 h = {(_Float16)f2.x, (_Float16)f2.y};
                Bs[r][cc] = as_f32(h);
            }
            __syncthreads();
#pragma unroll
            for (int kk = 0; kk < BK / 2; kk++) {
                float av[4], bv[4];
#pragma unroll
                for (int i = 0; i < 4; i++) av[i] = As[ty * 4 + i][kk];
#pragma unroll
                for (int j = 0; j < 4; j++) bv[j] = Bs[tx * 4 + j][kk];
#pragma unroll
                for (int i = 0; i < 4; i++)
#pragma unroll
                    for (int j = 0; j < 4; j++)
                        acc[i][j] = fdot2f(as_hf2(av[i]), as_hf2(bv[j]),
                                           acc[i][j]);
            }
        }
    }
    for (int i = 0; i < 4; i++) {
        int bb = b0 + ty * 4 + i;
        if (bb >= B_) continue;
        for (int j = 0; j < 4; j++) {
            int jj = j0 + tx * 4 + j;
            gates[(size_t)bb * 512 + jj] = acc[i][j] + base[jj];
        }
    }
}

// ---------------------------------------------------------------------------
// K5: elementwise LSTM state update from gates
// ---------------------------------------------------------------------------
__global__ void lstm_elem_kernel(const float* __restrict__ gates,
                                 const float* __restrict__ c_prev, int c_bcast,
                                 float* __restrict__ c_out,
                                 float* __restrict__ h_out, int B_) {
    int t = blockIdx.x * 256 + threadIdx.x;
    if (t >= B_ * D) return;
    int b = t >> 7, d = t & (D - 1);
    const float* g = gates + (size_t)b * 512;
    float ig = 1.f / (1.f + __expf(-g[d]));
    float fg = 1.f / (1.f + __expf(-g[128 + d]));
    float gg = tanhf(g[256 + d]);
    float og = 1.f / (1.f + __expf(-g[384 + d]));
    float cp = c_bcast ? c_prev[d] : c_prev[t];
    float c = fg * cp + ig * gg;
    c_out[t] = c;
    h_out[t] = og * tanhf(c);
}

// ---------------------------------------------------------------------------
// K6: f32 attention (R4 structure) + optional fused f32->fp16 emission of x.
// ---------------------------------------------------------------------------
__global__ __launch_bounds__(256, 2) void attn_kernel(
    const float* __restrict__ x, const float* __restrict__ q_src, int q_bcast,
    const int* __restrict__ row_ptr, float* __restrict__ out,
    float* __restrict__ final_out, int B_, _Float16* __restrict__ xh) {

    __shared__ float xs[WPB][2][TILE * D];  // 2 x 8 KB per wave
    __shared__ float qs[WPB][2][256];       // 2 x 1 KB per wave
    __shared__ float wsh[WPB][TILE];

    const int tid  = threadIdx.x;
    const int wave = tid >> 6;
    const int lane = tid & 63;
    const int NW   = gridDim.x * WPB;

    const int p    = lane >> 5;        // staging/acc parity
    const int sc   = lane & 31;        // slot / dim-group id
    const int n    = lane >> 2;        // node id (dot): 0..15
    const int qd   = lane & 3;         // dim quarter (dot)
    const int qdb  = qd << 3;
    const int qd2  = qd << 1;
    const int dacc = dperm(sc);
    const int qsrc = dperm_inv(sc);

    float* xb[2] = {xs[wave][0], xs[wave][1]};
    float* qb[2] = {qs[wave][0], qs[wave][1]};
    float* wsw   = wsh[wave];

    auto issue_tile = [&](int t0, int e_, float* dst) {
#pragma unroll
        for (int j = 0; j < 8; j++) {
            int row = 2 * j + p;
            int rg  = t0 + row;
            rg = (rg < e_) ? rg : (e_ - 1);
            int u = (sc - row) & 31;
            int col = dperm_inv(u);
            gload16(x + ((size_t)rg * D + (col << 2)), dst + j * 256);
        }
    };
    auto issue_q = [&](int bq, float* dst) {
        const float* qp = q_bcast ? q_src : q_src + (size_t)bq * D;
        gload16(qp + (qsrc << 2), dst);
    };

    const int S = out ? 1 : 2;
    int b = blockIdx.x * WPB + wave;
    if (b >= B_) return;

    unsigned long long se0 = sload2(row_ptr, b);
    int s = (int)(se0 & 0xffffffffull), e = (int)(se0 >> 32);
    int cur = 0, qc = 0, ps = 0;
    issue_q(b, qb[0]);
    if (s < e) issue_tile(s, e, xb[0]);

    while (1) {
        float m = -1e30f, lsum = 0.f;
        float ax = 0.f, ay = 0.f, az = 0.f, aw = 0.f;
        int sn = 0, en = 0;
        int bn = b + NW;
        int have_next = (bn < B_);

        if (s < e) {
            for (int t0 = s; t0 < e; t0 += TILE) {
                int nt = e - t0; nt = (nt < TILE) ? nt : TILE;
                int just;
                if (t0 + TILE < e) {
                    issue_tile(t0 + TILE, e, xb[cur ^ 1]);
                    just = 8;
                } else if (have_next) {
                    unsigned long long se2 = sload2(row_ptr, bn);
                    sn = (int)(se2 & 0xffffffffull); en = (int)(se2 >> 32);
                    issue_q(bn, qb[qc ^ 1]);
                    just = 1;
                    if (sn < en) { issue_tile(sn, en, xb[cur ^ 1]); just = 9; }
                } else {
                    just = 0;
                }
                wait_vm(just + ps); ps = 0;

                const float4* xw4 = (const float4*)xb[cur];
                const float4* qw4 = (const float4*)qb[qc];

                // fused convert: emit this tile as fp16, row-major
                if (xh) {
                    int row = n, qq = qd;        // reuse decomp: 16x4 lanes
                    float dw[16];
#pragma unroll
                    for (int i = 0; i < 8; i++) {
                        int sl = ((qq * 8 + ((i + 2 * qq) & 7)) + row) & 31;
                        float4 f = xw4[(row << 5) + sl];
                        hf2 h0 = {(_Float16)f.x, (_Float16)f.y};
                        hf2 h1 = {(_Float16)f.z, (_Float16)f.w};
                        dw[2 * i]     = as_f32(h0);
                        dw[2 * i + 1] = as_f32(h1);
                    }
                    int rowg = t0 + row;
                    rowg = (rowg < e) ? rowg : (e - 1);   // idempotent clamp
                    float4* xo = (float4*)((char*)xh +
                                 ((size_t)rowg * 256 + (qq << 6)));
                    xo[0] = make_float4(dw[0], dw[1], dw[2], dw[3]);
                    xo[1] = make_float4(dw[4], dw[5], dw[6], dw[7]);
                    xo[2] = make_float4(dw[8], dw[9], dw[10], dw[11]);
                    xo[3] = make_float4(dw[12], dw[13], dw[14], dw[15]);
                    ps += 4;
                }

                // dot: 4 lanes/node, 32 dims each; 2 accumulators
                float pd0 = 0.f, pd1 = 0.f;
#pragma unroll
                for (int j = 0; j < 8; j += 2) {
                    int sl0 = ((qdb | ((j + qd2) & 7)) + n) & 31;
                    int sl1 = ((qdb | ((j + 1 + qd2) & 7)) + n) & 31;
                    float4 xv0 = xw4[(n << 5) + sl0];
                    float4 qv0 = qw4[qdb | ((j + qd2) & 7)];
                    float4 xv1 = xw4[(n << 5) + sl1];
                    float4 qv1 = qw4[qdb | ((j + 1 + qd2) & 7)];
                    pd0 += xv0.x * qv0.x + xv0.y * qv0.y + xv0.z * qv0.z + xv0.w * qv0.w;
                    pd1 += xv1.x * qv1.x + xv1.y * qv1.y + xv1.z * qv1.z + xv1.w * qv1.w;
                }
                float pd = pd0 + pd1;
                pd += __shfl_xor(pd, 1);
                pd += __shfl_xor(pd, 2);
                float prod = (n < nt) ? pd : -1e30f;

                if (!__all(prod <= m + THR)) {
                    float tmax = prod;
#pragma unroll
                    for (int mk = 4; mk <= 32; mk <<= 1)
                        tmax = fmaxf(tmax, __shfl_xor(tmax, mk));
                    float m_new = fmaxf(m, tmax);
                    float r = __expf(m - m_new);
                    lsum *= r;
                    ax *= r; ay *= r; az *= r; aw *= r;
                    m = m_new;
                }
                float w = __expf(prod - m);

                float tsum = w;
#pragma unroll
                for (int mk = 4; mk <= 32; mk <<= 1)
                    tsum += __shfl_xor(tsum, mk);
                lsum += tsum;

                if (qd == 0) wsw[n] = w;

#pragma unroll
                for (int i = 0; i < 8; i++) {
                    int row = 2 * i + p;
                    float wt = wsw[row];
                    float4 xv = xw4[(row << 5) + ((dacc + row) & 31)];
                    ax += wt * xv.x; ay += wt * xv.y;
                    az += wt * xv.z; aw += wt * xv.w;
                }
                cur ^= 1;
            }
        } else {
            int just = 0;
            if (have_next) {
                unsigned long long se2 = sload2(row_ptr, bn);
                sn = (int)(se2 & 0xffffffffull); en = (int)(se2 >> 32);
                issue_q(bn, qb[qc ^ 1]);
                just = 1;
                if (sn < en) { issue_tile(sn, en, xb[cur ^ 1]); just = 9; cur ^= 1; }
            }
            wait_vm(just + ps); ps = 0;
        }

        // finalize graph b
        ax += __shfl_xor(ax, 32);
        ay += __shfl_xor(ay, 32);
        az += __shfl_xor(az, 32);
        aw += __shfl_xor(aw, 32);
        float inv = 1.f / (lsum + EPS);
        float4 o = {ax * inv, ay * inv, az * inv, aw * inv};
        if (p == 0) {
            if (out) {
                ((float4*)out)[(size_t)b * 32 + sc] = o;
            } else {
                const float4* q4r = (const float4*)qb[qc];
                float4 qv = q4r[dperm(sc)];
                float4* fo = (float4*)(final_out + (size_t)b * 256);
                fo[sc] = qv;
                fo[32 + sc] = o;
            }
        }
        ps += S;
        if (!have_next) break;
        b = bn; s = sn; e = en; qc ^= 1;
    }
}

// ---------------------------------------------------------------------------
// K7: fp16 attention (passes 2-3). TILE_H=32 rows (8 KB tiles, 8 gloads in
// flight — same pipeline depth as the f32 kernel). Rotation layout in 16B
// groups; v_dot2_f32_f16 dot; f32 accumulators.
// ---------------------------------------------------------------------------
__global__ __launch_bounds__(256, 2) void attn_h_kernel(
    const _Float16* __restrict__ xh, const float* __restrict__ q_src,
    const int* __restrict__ row_ptr, float* __restrict__ out,
    float* __restrict__ final_out, int B_) {

    __shared__ float xs[WPB][2][TILE_H * 64];  // 2 x 8 KB per wave
    __shared__ float qf[WPB][2][256];          // staged q f32 (1 KB incl dup)
    __shared__ float qh[WPB][64];              // q as half2 (256 B)
    __shared__ float wsh[WPB][TILE_H];

    const int tid  = threadIdx.x;
    const int wave = tid >> 6;
    const int lane = tid & 63;
    const int NW   = gridDim.x * WPB;

    const int n  = lane >> 1;    // dot: node 0..31
    const int h  = lane & 1;     // dot: dim half
    const int h8 = h << 3;
    const int g  = lane & 15;    // acc: 16B group (8 dims)
    const int pp = lane >> 4;    // acc: row phase 0..3

    float* xb[2] = {xs[wave][0], xs[wave][1]};
    float* qb[2] = {qf[wave][0], qf[wave][1]};
    float* qhw   = qh[wave];
    float* wsw   = wsh[wave];

    auto issue_tile = [&](int t0, int e_, float* dst) {
#pragma unroll
        for (int j = 0; j < 8; j++) {
            int idx = (j << 6) + lane;           // 0..511 slots
            int row = idx >> 4, s16 = idx & 15;
            int rg = t0 + row;
            rg = (rg < e_) ? rg : (e_ - 1);
            int gg = (s16 - row) & 15;           // pre-swizzled source group
            gload16((const char*)xh + ((size_t)rg << 8) + (gg << 4),
                    dst + (j << 8));
        }
    };
    auto issue_q = [&](int bq, float* dst) {
        gload16(q_src + ((size_t)bq << 7) + ((lane & 31) << 2), dst);
    };

    const int S = out ? 2 : 4;
    int b = blockIdx.x * WPB + wave;
    if (b >= B_) return;

    unsigned long long se0 = sload2(row_ptr, b);
    int s = (int)(se0 & 0xffffffffull), e = (int)(se0 >> 32);
    int cur = 0, qc = 0, ps = 0;
    issue_q(b, qb[0]);
    if (s < e) issue_tile(s, e, xb[0]);

    while (1) {
        float m = -1e30f, lsum = 0.f;
        float a[8] = {0.f, 0.f, 0.f, 0.f, 0.f, 0.f, 0.f, 0.f};
        int sn = 0, en = 0;
        int bn = b + NW;
        int have_next = (bn < B_);

        if (s < e) {
            for (int t0 = s; t0 < e; t0 += TILE_H) {
                int nt = e - t0; nt = (nt < TILE_H) ? nt : TILE_H;
                int just;
                if (t0 + TILE_H < e) {
                    issue_tile(t0 + TILE_H, e, xb[cur ^ 1]);
                    just = 8;
                } else if (have_next) {
                    unsigned long long se2 = sload2(row_ptr, bn);
                    sn = (int)(se2 & 0xffffffffull); en = (int)(se2 >> 32);
                    issue_q(bn, qb[qc ^ 1]);
                    just = 1;
                    if (sn < en) { issue_tile(sn, en, xb[cur ^ 1]); just = 9; }
                } else {
                    just = 0;
                }
                wait_vm(just + ps); ps = 0;

                if (t0 == s) {  // convert this graph's q: f32 -> half2
                    float2 f2 = ((const float2*)qb[qc])[lane];
                    hf2 hq = {(_Float16)f2.x, (_Float16)f2.y};
                    qhw[lane] = as_f32(hq);
                }

                const float4* xw4 = (const float4*)xb[cur];
                const float4* qh4 = (const float4*)qhw;

                // dot: 2 lanes/node, 64 dims each via fdot2
                float pd0 = 0.f, pd1 = 0.f;
#pragma unroll
                for (int j = 0; j < 8; j++) {
                    int gg = h8 + j;
                    float4 xv = xw4[(n << 4) + ((gg + n) & 15)];
                    float4 qv = qh4[gg];
                    pd0 = fdot2f(as_hf2(xv.x), as_hf2(qv.x), pd0);
                    pd1 = fdot2f(as_hf2(xv.y), as_hf2(qv.y), pd1);
                    pd0 = fdot2f(as_hf2(xv.z), as_hf2(qv.z), pd0);
                    pd1 = fdot2f(as_hf2(xv.w), as_hf2(qv.w), pd1);
                }
                float pd = pd0 + pd1;
                pd += __shfl_xor(pd, 1);
                float prod = (n < nt) ? pd : -1e30f;

                if (!__all(prod <= m + THR)) {
                    float tmax = prod;
#pragma unroll
                    for (int mk = 2; mk <= 32; mk <<= 1)
                        tmax = fmaxf(tmax, __shfl_xor(tmax, mk));
                    float m_new = fmaxf(m, tmax);
                    float r = __expf(m - m_new);
                    lsum *= r;
#pragma unroll
                    for (int k = 0; k < 8; k++) a[k] *= r;
                    m = m_new;
                }
                float w = __expf(prod - m);

                float tsum = w;
#pragma unroll
                for (int mk = 2; mk <= 32; mk <<= 1)
                    tsum += __shfl_xor(tsum, mk);
                lsum += tsum;

                if (h == 0) wsw[n] = w;

                // accumulate: lane owns group g (8 dims), rows 4i+pp
#pragma unroll
                for (int i = 0; i < 8; i++) {
                    int ro = (i << 2) + pp;
                    float wt = wsw[ro];
                    float4 xv = xw4[(ro << 4) + ((g + ro) & 15)];
                    hf2 h0 = as_hf2(xv.x), h1 = as_hf2(xv.y);
                    hf2 h2 = as_hf2(xv.z), h3 = as_hf2(xv.w);
                    a[0] += wt * (float)h0.x; a[1] += wt * (float)h0.y;
                    a[2] += wt * (float)h1.x; a[3] += wt * (float)h1.y;
                    a[4] += wt * (float)h2.x; a[5] += wt * (float)h2.y;
                    a[6] += wt * (float)h3.x; a[7] += wt * (float)h3.y;
                }
                cur ^= 1;
            }
        } else {
            int just = 0;
            if (have_next) {
                unsigned long long se2 = sload2(row_ptr, bn);
                sn = (int)(se2 & 0xffffffffull); en = (int)(se2 >> 32);
                issue_q(bn, qb[qc ^ 1]);
                just = 1;
                if (sn < en) { issue_tile(sn, en, xb[cur ^ 1]); just = 9; cur ^= 1; }
            }
            wait_vm(just + ps); ps = 0;
        }

        // finalize graph b: reduce over pp (4 lanes per group)
#pragma unroll
        for (int k = 0; k < 8; k++) {
            a[k] += __shfl_xor(a[k], 16);
            a[k] += __shfl_xor(a[k], 32);
        }
        float inv = 1.f / (lsum + EPS);
        if (pp == 0) {
            float4 o0 = {a[0] * inv, a[1] * inv, a[2] * inv, a[3] * inv};
            float4 o1 = {a[4] * inv, a[5] * inv, a[6] * inv, a[7] * inv};
            if (out) {
                float4* op = (float4*)(out + (size_t)b * D + (g << 3));
                op[0] = o0; op[1] = o1;
            } else {
                const float4* q4r = (const float4*)qb[qc];
                float4 q0 = q4r[g * 2], q1 = q4r[g * 2 + 1];
                float4* fo = (float4*)(final_out + (size_t)b * 256 + (g << 3));
                fo[0] = q0; fo[1] = q1;
                float4* fo2 = (float4*)(final_out + (size_t)b * 256 + D + (g << 3));
                fo2[0] = o0; fo2[1] = o1;
            }
        }
        ps += S;
        if (!have_next) break;
        b = bn; s = sn; e = en; qc ^= 1;
    }
}

// ---------------------------------------------------------------------------
extern "C" void kernel_launch(void* const* d_in, const int* in_sizes, int n_in,
                              void* d_out, int out_size, void* d_ws,
                              size_t ws_size, hipStream_t stream) {
    const float* x    = (const float*)d_in[0];
    const float* w_ih = (const float*)d_in[1];
    const float* w_hh = (const float*)d_in[2];
    const float* b_ih = (const float*)d_in[3];
    const float* b_hh = (const float*)d_in[4];
    const int*   n2g  = (const int*)d_in[5];

    int N_ = in_sizes[0] / D;     // 1,000,000
    int B_ = out_size / (2 * D);  // 10,000

    char* wsb = (char*)d_ws;
    size_t off = 0;
    auto carve = [&](size_t bytes) {
        void* pp = wsb + off;
        off = (off + bytes + 255) & ~(size_t)255;
        return pp;
    };
    int*   row_ptr = (int*)carve((size_t)(B_ + 1) * 4);
    float* b_sum   = (float*)carve(512 * 4);
    float* c1      = (float*)carve(D * 4);
    float* h1      = (float*)carve(D * 4);
    float* const2  = (float*)carve(512 * 4);
    float* W1      = (float*)carve((size_t)512 * D * 4);
    float* hbuf    = (float*)carve((size_t)B_ * D * 4);
    float* cbuf    = (float*)carve((size_t)B_ * D * 4);
    float* outbuf  = (float*)carve((size_t)B_ * D * 4);
    float* gates   = (float*)carve((size_t)B_ * 512 * 4);
    _Float16* xh   = (_Float16*)carve((size_t)N_ * D * 2);   // 256 MB
    bool use_half = (off <= ws_size);

    const float* W2 = w_ih + D;  // rows of w_ih, col offset 128, stride 256

    rowptr_kernel<<<(B_ + 1 + 255) / 256, 256, 0, stream>>>(n2g, N_, B_, row_ptr);
    init_consts_kernel<<<1, 512, 0, stream>>>(b_ih, b_hh, b_sum, c1, h1);
    init_w1_kernel<<<512, 128, 0, stream>>>(w_ih, w_hh, b_sum, h1, W1, const2);

    dim3 ggrid(512 / BN, (B_ + BM - 1) / BM);
    int  egrid = (B_ * D + 255) / 256;

    if (use_half) {
        // pass 1 (f32, fused fp16 emission)
        attn_kernel<<<NBLK, 256, 0, stream>>>(x, h1, 1, row_ptr, outbuf,
                                              nullptr, B_, xh);
        lstm_gemm_kernel<<<ggrid, 256, 0, stream>>>(outbuf, W2, 256, nullptr,
                                                    nullptr, 0, const2, gates, B_);
        lstm_elem_kernel<<<egrid, 256, 0, stream>>>(gates, c1, 1, cbuf, hbuf, B_);
        // pass 2 (fp16)
        attn_h_kernel<<<NBLK_H, 256, 0, stream>>>(xh, hbuf, row_ptr, outbuf,
                                                  nullptr, B_);
        lstm_gemm_kernel<<<ggrid, 256, 0, stream>>>(hbuf, W1, 128, outbuf, W2, 256,
                                                    b_sum, gates, B_);
        lstm_elem_kernel<<<egrid, 256, 0, stream>>>(gates, cbuf, 0, cbuf, hbuf, B_);
        // pass 3 (fp16, writes q_star)
        attn_h_kernel<<<NBLK_H, 256, 0, stream>>>(xh, hbuf, row_ptr, nullptr,
                                                  (float*)d_out, B_);
    } else {
        // fallback: all-f32 sequence
        attn_kernel<<<NBLK, 256, 0, stream>>>(x, h1, 1, row_ptr, outbuf,
                                              nullptr, B_, nullptr);
        lstm_gemm_kernel<<<ggrid, 256, 0, stream>>>(outbuf, W2, 256, nullptr,
                                                    nullptr, 0, const2, gates, B_);
        lstm_elem_kernel<<<egrid, 256, 0, stream>>>(gates, c1, 1, cbuf, hbuf, B_);
        attn_kernel<<<NBLK, 256, 0, stream>>>(x, hbuf, 0, row_ptr, outbuf,
                                              nullptr, B_, nullptr);
        lstm_gemm_kernel<<<ggrid, 256, 0, stream>>>(hbuf, W1, 128, outbuf, W2, 256,
                                                    b_sum, gates, B_);
        lstm_elem_kernel<<<egrid, 256, 0, stream>>>(gates, cbuf, 0, cbuf, hbuf, B_);
        attn_kernel<<<NBLK, 256, 0, stream>>>(x, hbuf, 0, row_ptr, nullptr,
                                              (float*)d_out, B_, nullptr);
    }
}

// Round 10
// 433.469 us; speedup vs baseline: 2.1221x; 1.0170x over previous
//
#include <hip/hip_runtime.h>

#define D 128
#define EPS 1e-10f
#define TILE 16
#define TILE_H 32
#define WPB 4
#define NBLK 512
#define NBLK_H 512
#define THR 14.0f

typedef _Float16 hf2 __attribute__((ext_vector_type(2)));

__device__ __forceinline__ hf2 as_hf2(float v) { return __builtin_bit_cast(hf2, v); }
__device__ __forceinline__ float as_f32(hf2 v) { return __builtin_bit_cast(float, v); }

__device__ __forceinline__ float fdot2f(hf2 a, hf2 b, float c) {
#if __has_builtin(__builtin_amdgcn_fdot2)
    return __builtin_amdgcn_fdot2(a, b, c, false);
#else
    return (float)a.x * (float)b.x + (float)a.y * (float)b.y + c;
#endif
}

// ---------------------------------------------------------------------------
// async global -> LDS, 16B per lane (dest = base + lane*16, linear)
// ---------------------------------------------------------------------------
__device__ __forceinline__ void gload16(const void* g, void* l) {
    __builtin_amdgcn_global_load_lds(
        (const __attribute__((address_space(1))) void*)g,
        (__attribute__((address_space(3))) void*)l, 16, 0, 0);
}

// scalar load of row_ptr[idx], row_ptr[idx+1] (lgkmcnt path)
__device__ __forceinline__ unsigned long long sload2(const int* rp, int idx) {
    unsigned long long r;
    int off = __builtin_amdgcn_readfirstlane(idx << 2);
    asm volatile("s_load_dwordx2 %0, %1, %2\n\ts_waitcnt lgkmcnt(0)"
                 : "=s"(r) : "s"(rp), "s"(off) : "memory");
    return r;
}

__device__ __forceinline__ void wait_vm(int nn) {
    switch (nn) {
    case 0:  asm volatile("s_waitcnt vmcnt(0)"  ::: "memory"); break;
    case 1:  asm volatile("s_waitcnt vmcnt(1)"  ::: "memory"); break;
    case 2:  asm volatile("s_waitcnt vmcnt(2)"  ::: "memory"); break;
    case 3:  asm volatile("s_waitcnt vmcnt(3)"  ::: "memory"); break;
    case 4:  asm volatile("s_waitcnt vmcnt(4)"  ::: "memory"); break;
    case 5:  asm volatile("s_waitcnt vmcnt(5)"  ::: "memory"); break;
    case 6:  asm volatile("s_waitcnt vmcnt(6)"  ::: "memory"); break;
    case 7:  asm volatile("s_waitcnt vmcnt(7)"  ::: "memory"); break;
    case 8:  asm volatile("s_waitcnt vmcnt(8)"  ::: "memory"); break;
    case 9:  asm volatile("s_waitcnt vmcnt(9)"  ::: "memory"); break;
    case 10: asm volatile("s_waitcnt vmcnt(10)" ::: "memory"); break;
    case 11: asm volatile("s_waitcnt vmcnt(11)" ::: "memory"); break;
    case 12: asm volatile("s_waitcnt vmcnt(12)" ::: "memory"); break;
    case 13: asm volatile("s_waitcnt vmcnt(13)" ::: "memory"); break;
    case 14: asm volatile("s_waitcnt vmcnt(14)" ::: "memory"); break;
    case 15: asm volatile("s_waitcnt vmcnt(15)" ::: "memory"); break;
    case 16: asm volatile("s_waitcnt vmcnt(16)" ::: "memory"); break;
    case 17: asm volatile("s_waitcnt vmcnt(17)" ::: "memory"); break;
    case 18: asm volatile("s_waitcnt vmcnt(18)" ::: "memory"); break;
    case 19: asm volatile("s_waitcnt vmcnt(19)" ::: "memory"); break;
    case 20: asm volatile("s_waitcnt vmcnt(20)" ::: "memory"); break;
    default: asm volatile("s_waitcnt vmcnt(0)"  ::: "memory"); break;
    }
}

// bit-mixed dim-group -> slot permutation (f32 kernel, 4-float groups)
__device__ __forceinline__ int dperm(int d) {
    return (d & 24) | ((d + 2 * (d >> 3)) & 7);
}
__device__ __forceinline__ int dperm_inv(int u) {
    int q = u >> 3;
    return (q << 3) | ((u - 2 * q) & 7);
}

// ---------------------------------------------------------------------------
// K1: row_ptr via binary search (node2graph sorted)
// ---------------------------------------------------------------------------
__global__ void rowptr_kernel(const int* __restrict__ n2g, int N_, int B_,
                              int* __restrict__ row_ptr) {
    int b = blockIdx.x * 256 + threadIdx.x;
    if (b > B_) return;
    if (b == B_) { row_ptr[b] = N_; return; }
    int lo = 0, hi = N_;
    while (lo < hi) {
        int mid = (lo + hi) >> 1;
        if (n2g[mid] < b) lo = mid + 1; else hi = mid;
    }
    row_ptr[b] = lo;
}

// ---------------------------------------------------------------------------
// K2: b_sum = b_ih + b_hh; step-1 constants h1, c1
// ---------------------------------------------------------------------------
__global__ void init_consts_kernel(const float* __restrict__ b_ih,
                                   const float* __restrict__ b_hh,
                                   float* __restrict__ b_sum,
                                   float* __restrict__ c1,
                                   float* __restrict__ h1) {
    int t = threadIdx.x;  // 512 threads, 1 block
    __shared__ float bs[512];
    float v = b_ih[t] + b_hh[t];
    b_sum[t] = v;
    bs[t] = v;
    __syncthreads();
    if (t < D) {
        float ig = 1.f / (1.f + __expf(-bs[t]));
        float gg = tanhf(bs[256 + t]);
        float c  = ig * gg;
        float og = 1.f / (1.f + __expf(-bs[384 + t]));
        c1[t] = c;
        h1[t] = og * tanhf(c);
    }
}

// ---------------------------------------------------------------------------
// K3: W1 = w_ih[:, :D] + w_hh; const2 = b_sum + W1 @ h1
// ---------------------------------------------------------------------------
__global__ void init_w1_kernel(const float* __restrict__ w_ih,
                               const float* __restrict__ w_hh,
                               const float* __restrict__ b_sum,
                               const float* __restrict__ h1,
                               float* __restrict__ W1,
                               float* __restrict__ const2) {
    int j = blockIdx.x, k = threadIdx.x;
    float w = w_ih[j * 256 + k] + w_hh[j * 128 + k];
    W1[j * 128 + k] = w;
    __shared__ float red[128];
    red[k] = w * h1[k];
    __syncthreads();
    for (int s = 64; s > 0; s >>= 1) {
        if (k < s) red[k] += red[k + s];
        __syncthreads();
    }
    if (k == 0) const2[j] = b_sum[j] + red[0];
}

// ---------------------------------------------------------------------------
// K4: tiled GEMM with packed-fp16 v_dot2_f32_f16 inner loop (f32 accumulate).
// gates[b][j] = base[j] + A1[b]·Wa[j] (+ A2[b]·Wb[j])
// ---------------------------------------------------------------------------
#define BM 64
#define BN 64
#define BK 32
__global__ __launch_bounds__(256) void lstm_gemm_kernel(
    const float* __restrict__ A1, const float* __restrict__ Wa, int wa_stride,
    const float* __restrict__ A2, const float* __restrict__ Wb, int wb_stride,
    const float* __restrict__ base, float* __restrict__ gates, int B_) {
    __shared__ float As[BM][BK / 2 + 1];   // packed half2
    __shared__ float Bs[BN][BK / 2 + 1];
    int b0 = blockIdx.y * BM;
    int j0 = blockIdx.x * BN;
    int tid = threadIdx.x;
    int tx = tid & 15, ty = tid >> 4;
    float acc[4][4] = {};
    int nphase = A2 ? 2 : 1;
    for (int phase = 0; phase < nphase; phase++) {
        const float* A = phase ? A2 : A1;
        const float* W = phase ? Wb : Wa;
        int ws = phase ? wb_stride : wa_stride;
        for (int k0 = 0; k0 < 128; k0 += BK) {
            __syncthreads();
            for (int i = tid; i < BM * (BK / 2); i += 256) {
                int r = i >> 4, cc = i & 15;
                int bb = b0 + r;
                float2 f2 = (bb < B_)
                    ? *(const float2*)&A[(size_t)bb * D + k0 + 2 * cc]
                    : make_float2(0.f, 0.f);
                hf2 h = {(_Float16)f2.x, (_Float16)f2.y};
                As[r][cc] = as_f32(h);
            }
            for (int i = tid; i < BN * (BK / 2); i += 256) {
                int r = i >> 4, cc = i & 15;
                float2 f2 = *(const float2*)&W[(size_t)(j0 + r) * ws + k0 + 2 * cc];
                hf2 h = {(_Float16)f2.x, (_Float16)f2.y};
                Bs[r][cc] = as_f32(h);
            }
            __syncthreads();
#pragma unroll
            for (int kk = 0; kk < BK / 2; kk++) {
                float av[4], bv[4];
#pragma unroll
                for (int i = 0; i < 4; i++) av[i] = As[ty * 4 + i][kk];
#pragma unroll
                for (int j = 0; j < 4; j++) bv[j] = Bs[tx * 4 + j][kk];
#pragma unroll
                for (int i = 0; i < 4; i++)
#pragma unroll
                    for (int j = 0; j < 4; j++)
                        acc[i][j] = fdot2f(as_hf2(av[i]), as_hf2(bv[j]),
                                           acc[i][j]);
            }
        }
    }
    for (int i = 0; i < 4; i++) {
        int bb = b0 + ty * 4 + i;
        if (bb >= B_) continue;
        for (int j = 0; j < 4; j++) {
            int jj = j0 + tx * 4 + j;
            gates[(size_t)bb * 512 + jj] = acc[i][j] + base[jj];
        }
    }
}

// ---------------------------------------------------------------------------
// K5: elementwise LSTM state update from gates
// ---------------------------------------------------------------------------
__global__ void lstm_elem_kernel(const float* __restrict__ gates,
                                 const float* __restrict__ c_prev, int c_bcast,
                                 float* __restrict__ c_out,
                                 float* __restrict__ h_out, int B_) {
    int t = blockIdx.x * 256 + threadIdx.x;
    if (t >= B_ * D) return;
    int b = t >> 7, d = t & (D - 1);
    const float* g = gates + (size_t)b * 512;
    float ig = 1.f / (1.f + __expf(-g[d]));
    float fg = 1.f / (1.f + __expf(-g[128 + d]));
    float gg = tanhf(g[256 + d]);
    float og = 1.f / (1.f + __expf(-g[384 + d]));
    float cp = c_bcast ? c_prev[d] : c_prev[t];
    float c = fg * cp + ig * gg;
    c_out[t] = c;
    h_out[t] = og * tanhf(c);
}

// ---------------------------------------------------------------------------
// K6: f32 attention (R4 structure) + optional fused f32->fp16 emission of x.
// ---------------------------------------------------------------------------
__global__ __launch_bounds__(256, 2) void attn_kernel(
    const float* __restrict__ x, const float* __restrict__ q_src, int q_bcast,
    const int* __restrict__ row_ptr, float* __restrict__ out,
    float* __restrict__ final_out, int B_, _Float16* __restrict__ xh) {

    __shared__ float xs[WPB][2][TILE * D];  // 2 x 8 KB per wave
    __shared__ float qs[WPB][2][256];       // 2 x 1 KB per wave
    __shared__ float wsh[WPB][TILE];

    const int tid  = threadIdx.x;
    const int wave = tid >> 6;
    const int lane = tid & 63;
    const int NW   = gridDim.x * WPB;

    const int p    = lane >> 5;        // staging/acc parity
    const int sc   = lane & 31;        // slot / dim-group id
    const int n    = lane >> 2;        // node id (dot): 0..15
    const int qd   = lane & 3;         // dim quarter (dot)
    const int qdb  = qd << 3;
    const int qd2  = qd << 1;
    const int dacc = dperm(sc);
    const int qsrc = dperm_inv(sc);

    float* xb[2] = {xs[wave][0], xs[wave][1]};
    float* qb[2] = {qs[wave][0], qs[wave][1]};
    float* wsw   = wsh[wave];

    auto issue_tile = [&](int t0, int e_, float* dst) {
#pragma unroll
        for (int j = 0; j < 8; j++) {
            int row = 2 * j + p;
            int rg  = t0 + row;
            rg = (rg < e_) ? rg : (e_ - 1);
            int u = (sc - row) & 31;
            int col = dperm_inv(u);
            gload16(x + ((size_t)rg * D + (col << 2)), dst + j * 256);
        }
    };
    auto issue_q = [&](int bq, float* dst) {
        const float* qp = q_bcast ? q_src : q_src + (size_t)bq * D;
        gload16(qp + (qsrc << 2), dst);
    };

    const int S = out ? 1 : 2;
    int b = blockIdx.x * WPB + wave;
    if (b >= B_) return;

    unsigned long long se0 = sload2(row_ptr, b);
    int s = (int)(se0 & 0xffffffffull), e = (int)(se0 >> 32);
    int cur = 0, qc = 0, ps = 0;
    issue_q(b, qb[0]);
    if (s < e) issue_tile(s, e, xb[0]);

    while (1) {
        float m = -1e30f, lsum = 0.f;
        float ax = 0.f, ay = 0.f, az = 0.f, aw = 0.f;
        int sn = 0, en = 0;
        int bn = b + NW;
        int have_next = (bn < B_);

        if (s < e) {
            for (int t0 = s; t0 < e; t0 += TILE) {
                int nt = e - t0; nt = (nt < TILE) ? nt : TILE;
                int just;
                if (t0 + TILE < e) {
                    issue_tile(t0 + TILE, e, xb[cur ^ 1]);
                    just = 8;
                } else if (have_next) {
                    unsigned long long se2 = sload2(row_ptr, bn);
                    sn = (int)(se2 & 0xffffffffull); en = (int)(se2 >> 32);
                    issue_q(bn, qb[qc ^ 1]);
                    just = 1;
                    if (sn < en) { issue_tile(sn, en, xb[cur ^ 1]); just = 9; }
                } else {
                    just = 0;
                }
                wait_vm(just + ps); ps = 0;

                const float4* xw4 = (const float4*)xb[cur];
                const float4* qw4 = (const float4*)qb[qc];

                // fused convert: emit this tile as fp16, row-major
                if (xh) {
                    int row = n, qq = qd;        // reuse decomp: 16x4 lanes
                    float dw[16];
#pragma unroll
                    for (int i = 0; i < 8; i++) {
                        int sl = ((qq * 8 + ((i + 2 * qq) & 7)) + row) & 31;
                        float4 f = xw4[(row << 5) + sl];
                        hf2 h0 = {(_Float16)f.x, (_Float16)f.y};
                        hf2 h1 = {(_Float16)f.z, (_Float16)f.w};
                        dw[2 * i]     = as_f32(h0);
                        dw[2 * i + 1] = as_f32(h1);
                    }
                    int rowg = t0 + row;
                    rowg = (rowg < e) ? rowg : (e - 1);   // idempotent clamp
                    float4* xo = (float4*)((char*)xh +
                                 ((size_t)rowg * 256 + (qq << 6)));
                    xo[0] = make_float4(dw[0], dw[1], dw[2], dw[3]);
                    xo[1] = make_float4(dw[4], dw[5], dw[6], dw[7]);
                    xo[2] = make_float4(dw[8], dw[9], dw[10], dw[11]);
                    xo[3] = make_float4(dw[12], dw[13], dw[14], dw[15]);
                    ps += 4;
                }

                // dot: 4 lanes/node, 32 dims each; 2 accumulators
                float pd0 = 0.f, pd1 = 0.f;
#pragma unroll
                for (int j = 0; j < 8; j += 2) {
                    int sl0 = ((qdb | ((j + qd2) & 7)) + n) & 31;
                    int sl1 = ((qdb | ((j + 1 + qd2) & 7)) + n) & 31;
                    float4 xv0 = xw4[(n << 5) + sl0];
                    float4 qv0 = qw4[qdb | ((j + qd2) & 7)];
                    float4 xv1 = xw4[(n << 5) + sl1];
                    float4 qv1 = qw4[qdb | ((j + 1 + qd2) & 7)];
                    pd0 += xv0.x * qv0.x + xv0.y * qv0.y + xv0.z * qv0.z + xv0.w * qv0.w;
                    pd1 += xv1.x * qv1.x + xv1.y * qv1.y + xv1.z * qv1.z + xv1.w * qv1.w;
                }
                float pd = pd0 + pd1;
                pd += __shfl_xor(pd, 1);
                pd += __shfl_xor(pd, 2);
                float prod = (n < nt) ? pd : -1e30f;

                if (!__all(prod <= m + THR)) {
                    float tmax = prod;
#pragma unroll
                    for (int mk = 4; mk <= 32; mk <<= 1)
                        tmax = fmaxf(tmax, __shfl_xor(tmax, mk));
                    float m_new = fmaxf(m, tmax);
                    float r = __expf(m - m_new);
                    lsum *= r;
                    ax *= r; ay *= r; az *= r; aw *= r;
                    m = m_new;
                }
                float w = __expf(prod - m);

                float tsum = w;
#pragma unroll
                for (int mk = 4; mk <= 32; mk <<= 1)
                    tsum += __shfl_xor(tsum, mk);
                lsum += tsum;

                if (qd == 0) wsw[n] = w;

#pragma unroll
                for (int i = 0; i < 8; i++) {
                    int row = 2 * i + p;
                    float wt = wsw[row];
                    float4 xv = xw4[(row << 5) + ((dacc + row) & 31)];
                    ax += wt * xv.x; ay += wt * xv.y;
                    az += wt * xv.z; aw += wt * xv.w;
                }
                cur ^= 1;
            }
        } else {
            int just = 0;
            if (have_next) {
                unsigned long long se2 = sload2(row_ptr, bn);
                sn = (int)(se2 & 0xffffffffull); en = (int)(se2 >> 32);
                issue_q(bn, qb[qc ^ 1]);
                just = 1;
                if (sn < en) { issue_tile(sn, en, xb[cur ^ 1]); just = 9; cur ^= 1; }
            }
            wait_vm(just + ps); ps = 0;
        }

        // finalize graph b
        ax += __shfl_xor(ax, 32);
        ay += __shfl_xor(ay, 32);
        az += __shfl_xor(az, 32);
        aw += __shfl_xor(aw, 32);
        float inv = 1.f / (lsum + EPS);
        float4 o = {ax * inv, ay * inv, az * inv, aw * inv};
        if (p == 0) {
            if (out) {
                ((float4*)out)[(size_t)b * 32 + sc] = o;
            } else {
                const float4* q4r = (const float4*)qb[qc];
                float4 qv = q4r[dperm(sc)];
                float4* fo = (float4*)(final_out + (size_t)b * 256);
                fo[sc] = qv;
                fo[32 + sc] = o;
            }
        }
        ps += S;
        if (!have_next) break;
        b = bn; s = sn; e = en; qc ^= 1;
    }
}

// ---------------------------------------------------------------------------
// K7: fp16 attention (passes 2-3). TILE_H=32 rows (8 KB tiles, 8 gloads in
// flight). Rotation layout in 16B groups; v_dot2_f32_f16 dot; f32 accum.
// Grid = 512 blocks = exactly 2 blocks/CU residency (73.5 KB LDS) — no tail.
// ---------------------------------------------------------------------------
__global__ __launch_bounds__(256, 2) void attn_h_kernel(
    const _Float16* __restrict__ xh, const float* __restrict__ q_src,
    const int* __restrict__ row_ptr, float* __restrict__ out,
    float* __restrict__ final_out, int B_) {

    __shared__ float xs[WPB][2][TILE_H * 64];  // 2 x 8 KB per wave
    __shared__ float qf[WPB][2][256];          // staged q f32 (1 KB incl dup)
    __shared__ float qh[WPB][64];              // q as half2 (256 B)
    __shared__ float wsh[WPB][TILE_H];

    const int tid  = threadIdx.x;
    const int wave = tid >> 6;
    const int lane = tid & 63;
    const int NW   = gridDim.x * WPB;

    const int n  = lane >> 1;    // dot: node 0..31
    const int h  = lane & 1;     // dot: dim half
    const int h8 = h << 3;
    const int g  = lane & 15;    // acc: 16B group (8 dims)
    const int pp = lane >> 4;    // acc: row phase 0..3

    float* xb[2] = {xs[wave][0], xs[wave][1]};
    float* qb[2] = {qf[wave][0], qf[wave][1]};
    float* qhw   = qh[wave];
    float* wsw   = wsh[wave];

    auto issue_tile = [&](int t0, int e_, float* dst) {
#pragma unroll
        for (int j = 0; j < 8; j++) {
            int idx = (j << 6) + lane;           // 0..511 slots
            int row = idx >> 4, s16 = idx & 15;
            int rg = t0 + row;
            rg = (rg < e_) ? rg : (e_ - 1);
            int gg = (s16 - row) & 15;           // pre-swizzled source group
            gload16((const char*)xh + ((size_t)rg << 8) + (gg << 4),
                    dst + (j << 8));
        }
    };
    auto issue_q = [&](int bq, float* dst) {
        gload16(q_src + ((size_t)bq << 7) + ((lane & 31) << 2), dst);
    };

    const int S = out ? 2 : 4;
    int b = blockIdx.x * WPB + wave;
    if (b >= B_) return;

    unsigned long long se0 = sload2(row_ptr, b);
    int s = (int)(se0 & 0xffffffffull), e = (int)(se0 >> 32);
    int cur = 0, qc = 0, ps = 0;
    issue_q(b, qb[0]);
    if (s < e) issue_tile(s, e, xb[0]);

    while (1) {
        float m = -1e30f, lsum = 0.f;
        float a[8] = {0.f, 0.f, 0.f, 0.f, 0.f, 0.f, 0.f, 0.f};
        int sn = 0, en = 0;
        int bn = b + NW;
        int have_next = (bn < B_);

        if (s < e) {
            for (int t0 = s; t0 < e; t0 += TILE_H) {
                int nt = e - t0; nt = (nt < TILE_H) ? nt : TILE_H;
                int just;
                if (t0 + TILE_H < e) {
                    issue_tile(t0 + TILE_H, e, xb[cur ^ 1]);
                    just = 8;
                } else if (have_next) {
                    unsigned long long se2 = sload2(row_ptr, bn);
                    sn = (int)(se2 & 0xffffffffull); en = (int)(se2 >> 32);
                    issue_q(bn, qb[qc ^ 1]);
                    just = 1;
                    if (sn < en) { issue_tile(sn, en, xb[cur ^ 1]); just = 9; }
                } else {
                    just = 0;
                }
                wait_vm(just + ps); ps = 0;

                if (t0 == s) {  // convert this graph's q: f32 -> half2
                    float2 f2 = ((const float2*)qb[qc])[lane];
                    hf2 hq = {(_Float16)f2.x, (_Float16)f2.y};
                    qhw[lane] = as_f32(hq);
                }

                const float4* xw4 = (const float4*)xb[cur];
                const float4* qh4 = (const float4*)qhw;

                // dot: 2 lanes/node, 64 dims each via fdot2
                float pd0 = 0.f, pd1 = 0.f;
#pragma unroll
                for (int j = 0; j < 8; j++) {
                    int gg = h8 + j;
                    float4 xv = xw4[(n << 4) + ((gg + n) & 15)];
                    float4 qv = qh4[gg];
                    pd0 = fdot2f(as_hf2(xv.x), as_hf2(qv.x), pd0);
                    pd1 = fdot2f(as_hf2(xv.y), as_hf2(qv.y), pd1);
                    pd0 = fdot2f(as_hf2(xv.z), as_hf2(qv.z), pd0);
                    pd1 = fdot2f(as_hf2(xv.w), as_hf2(qv.w), pd1);
                }
                float pd = pd0 + pd1;
                pd += __shfl_xor(pd, 1);
                float prod = (n < nt) ? pd : -1e30f;

                if (!__all(prod <= m + THR)) {
                    float tmax = prod;
#pragma unroll
                    for (int mk = 2; mk <= 32; mk <<= 1)
                        tmax = fmaxf(tmax, __shfl_xor(tmax, mk));
                    float m_new = fmaxf(m, tmax);
                    float r = __expf(m - m_new);
                    lsum *= r;
#pragma unroll
                    for (int k = 0; k < 8; k++) a[k] *= r;
                    m = m_new;
                }
                float w = __expf(prod - m);

                float tsum = w;
#pragma unroll
                for (int mk = 2; mk <= 32; mk <<= 1)
                    tsum += __shfl_xor(tsum, mk);
                lsum += tsum;

                if (h == 0) wsw[n] = w;

                // accumulate: lane owns group g (8 dims), rows 4i+pp
#pragma unroll
                for (int i = 0; i < 8; i++) {
                    int ro = (i << 2) + pp;
                    float wt = wsw[ro];
                    float4 xv = xw4[(ro << 4) + ((g + ro) & 15)];
                    hf2 h0 = as_hf2(xv.x), h1 = as_hf2(xv.y);
                    hf2 h2 = as_hf2(xv.z), h3 = as_hf2(xv.w);
                    a[0] += wt * (float)h0.x; a[1] += wt * (float)h0.y;
                    a[2] += wt * (float)h1.x; a[3] += wt * (float)h1.y;
                    a[4] += wt * (float)h2.x; a[5] += wt * (float)h2.y;
                    a[6] += wt * (float)h3.x; a[7] += wt * (float)h3.y;
                }
                cur ^= 1;
            }
        } else {
            int just = 0;
            if (have_next) {
                unsigned long long se2 = sload2(row_ptr, bn);
                sn = (int)(se2 & 0xffffffffull); en = (int)(se2 >> 32);
                issue_q(bn, qb[qc ^ 1]);
                just = 1;
                if (sn < en) { issue_tile(sn, en, xb[cur ^ 1]); just = 9; cur ^= 1; }
            }
            wait_vm(just + ps); ps = 0;
        }

        // finalize graph b: reduce over pp (4 lanes per group)
#pragma unroll
        for (int k = 0; k < 8; k++) {
            a[k] += __shfl_xor(a[k], 16);
            a[k] += __shfl_xor(a[k], 32);
        }
        float inv = 1.f / (lsum + EPS);
        if (pp == 0) {
            float4 o0 = {a[0] * inv, a[1] * inv, a[2] * inv, a[3] * inv};
            float4 o1 = {a[4] * inv, a[5] * inv, a[6] * inv, a[7] * inv};
            if (out) {
                float4* op = (float4*)(out + (size_t)b * D + (g << 3));
                op[0] = o0; op[1] = o1;
            } else {
                const float4* q4r = (const float4*)qb[qc];
                float4 q0 = q4r[g * 2], q1 = q4r[g * 2 + 1];
                float4* fo = (float4*)(final_out + (size_t)b * 256 + (g << 3));
                fo[0] = q0; fo[1] = q1;
                float4* fo2 = (float4*)(final_out + (size_t)b * 256 + D + (g << 3));
                fo2[0] = o0; fo2[1] = o1;
            }
        }
        ps += S;
        if (!have_next) break;
        b = bn; s = sn; e = en; qc ^= 1;
    }
}

// ---------------------------------------------------------------------------
extern "C" void kernel_launch(void* const* d_in, const int* in_sizes, int n_in,
                              void* d_out, int out_size, void* d_ws,
                              size_t ws_size, hipStream_t stream) {
    const float* x    = (const float*)d_in[0];
    const float* w_ih = (const float*)d_in[1];
    const float* w_hh = (const float*)d_in[2];
    const float* b_ih = (const float*)d_in[3];
    const float* b_hh = (const float*)d_in[4];
    const int*   n2g  = (const int*)d_in[5];

    int N_ = in_sizes[0] / D;     // 1,000,000
    int B_ = out_size / (2 * D);  // 10,000

    char* wsb = (char*)d_ws;
    size_t off = 0;
    auto carve = [&](size_t bytes) {
        void* pp = wsb + off;
        off = (off + bytes + 255) & ~(size_t)255;
        return pp;
    };
    int*   row_ptr = (int*)carve((size_t)(B_ + 1) * 4);
    float* b_sum   = (float*)carve(512 * 4);
    float* c1      = (float*)carve(D * 4);
    float* h1      = (float*)carve(D * 4);
    float* const2  = (float*)carve(512 * 4);
    float* W1      = (float*)carve((size_t)512 * D * 4);
    float* hbuf    = (float*)carve((size_t)B_ * D * 4);
    float* cbuf    = (float*)carve((size_t)B_ * D * 4);
    float* outbuf  = (float*)carve((size_t)B_ * D * 4);
    float* gates   = (float*)carve((size_t)B_ * 512 * 4);
    _Float16* xh   = (_Float16*)carve((size_t)N_ * D * 2);   // 256 MB
    bool use_half = (off <= ws_size);

    const float* W2 = w_ih + D;  // rows of w_ih, col offset 128, stride 256

    rowptr_kernel<<<(B_ + 1 + 255) / 256, 256, 0, stream>>>(n2g, N_, B_, row_ptr);
    init_consts_kernel<<<1, 512, 0, stream>>>(b_ih, b_hh, b_sum, c1, h1);
    init_w1_kernel<<<512, 128, 0, stream>>>(w_ih, w_hh, b_sum, h1, W1, const2);

    dim3 ggrid(512 / BN, (B_ + BM - 1) / BM);
    int  egrid = (B_ * D + 255) / 256;

    if (use_half) {
        // pass 1 (f32, fused fp16 emission)
        attn_kernel<<<NBLK, 256, 0, stream>>>(x, h1, 1, row_ptr, outbuf,
                                              nullptr, B_, xh);
        lstm_gemm_kernel<<<ggrid, 256, 0, stream>>>(outbuf, W2, 256, nullptr,
                                                    nullptr, 0, const2, gates, B_);
        lstm_elem_kernel<<<egrid, 256, 0, stream>>>(gates, c1, 1, cbuf, hbuf, B_);
        // pass 2 (fp16)
        attn_h_kernel<<<NBLK_H, 256, 0, stream>>>(xh, hbuf, row_ptr, outbuf,
                                                  nullptr, B_);
        lstm_gemm_kernel<<<ggrid, 256, 0, stream>>>(hbuf, W1, 128, outbuf, W2, 256,
                                                    b_sum, gates, B_);
        lstm_elem_kernel<<<egrid, 256, 0, stream>>>(gates, cbuf, 0, cbuf, hbuf, B_);
        // pass 3 (fp16, writes q_star)
        attn_h_kernel<<<NBLK_H, 256, 0, stream>>>(xh, hbuf, row_ptr, nullptr,
                                                  (float*)d_out, B_);
    } else {
        // fallback: all-f32 sequence
        attn_kernel<<<NBLK, 256, 0, stream>>>(x, h1, 1, row_ptr, outbuf,
                                              nullptr, B_, nullptr);
        lstm_gemm_kernel<<<ggrid, 256, 0, stream>>>(outbuf, W2, 256, nullptr,
                                                    nullptr, 0, const2, gates, B_);
        lstm_elem_kernel<<<egrid, 256, 0, stream>>>(gates, c1, 1, cbuf, hbuf, B_);
        attn_kernel<<<NBLK, 256, 0, stream>>>(x, hbuf, 0, row_ptr, outbuf,
                                              nullptr, B_, nullptr);
        lstm_gemm_kernel<<<ggrid, 256, 0, stream>>>(hbuf, W1, 128, outbuf, W2, 256,
                                                    b_sum, gates, B_);
        lstm_elem_kernel<<<egrid, 256, 0, stream>>>(gates, cbuf, 0, cbuf, hbuf, B_);
        attn_kernel<<<NBLK, 256, 0, stream>>>(x, hbuf, 0, row_ptr, nullptr,
                                              (float*)d_out, B_, nullptr);
    }
}

// Round 11
// 407.675 us; speedup vs baseline: 2.2563x; 1.0633x over previous
//
#include <hip/hip_runtime.h>

#define D 128
#define EPS 1e-10f
#define TILE 16
#define TILE_H 32
#define WPB 4
#define NBLK 512
#define NBLK_H 512
#define THR 14.0f

typedef _Float16 hf2 __attribute__((ext_vector_type(2)));

__device__ __forceinline__ hf2 as_hf2(float v) { return __builtin_bit_cast(hf2, v); }
__device__ __forceinline__ float as_f32(hf2 v) { return __builtin_bit_cast(float, v); }

__device__ __forceinline__ float fdot2f(hf2 a, hf2 b, float c) {
#if __has_builtin(__builtin_amdgcn_fdot2)
    return __builtin_amdgcn_fdot2(a, b, c, false);
#else
    return (float)a.x * (float)b.x + (float)a.y * (float)b.y + c;
#endif
}

// ---------------------------------------------------------------------------
// async global -> LDS, 16B per lane (dest = base + lane*16, linear)
// ---------------------------------------------------------------------------
__device__ __forceinline__ void gload16(const void* g, void* l) {
    __builtin_amdgcn_global_load_lds(
        (const __attribute__((address_space(1))) void*)g,
        (__attribute__((address_space(3))) void*)l, 16, 0, 0);
}

// scalar load of row_ptr[idx], row_ptr[idx+1] (lgkmcnt path)
__device__ __forceinline__ unsigned long long sload2(const int* rp, int idx) {
    unsigned long long r;
    int off = __builtin_amdgcn_readfirstlane(idx << 2);
    asm volatile("s_load_dwordx2 %0, %1, %2\n\ts_waitcnt lgkmcnt(0)"
                 : "=s"(r) : "s"(rp), "s"(off) : "memory");
    return r;
}

__device__ __forceinline__ void wait_vm(int nn) {
    switch (nn) {
    case 0:  asm volatile("s_waitcnt vmcnt(0)"  ::: "memory"); break;
    case 1:  asm volatile("s_waitcnt vmcnt(1)"  ::: "memory"); break;
    case 2:  asm volatile("s_waitcnt vmcnt(2)"  ::: "memory"); break;
    case 3:  asm volatile("s_waitcnt vmcnt(3)"  ::: "memory"); break;
    case 4:  asm volatile("s_waitcnt vmcnt(4)"  ::: "memory"); break;
    case 5:  asm volatile("s_waitcnt vmcnt(5)"  ::: "memory"); break;
    case 6:  asm volatile("s_waitcnt vmcnt(6)"  ::: "memory"); break;
    case 7:  asm volatile("s_waitcnt vmcnt(7)"  ::: "memory"); break;
    case 8:  asm volatile("s_waitcnt vmcnt(8)"  ::: "memory"); break;
    case 9:  asm volatile("s_waitcnt vmcnt(9)"  ::: "memory"); break;
    case 10: asm volatile("s_waitcnt vmcnt(10)" ::: "memory"); break;
    case 11: asm volatile("s_waitcnt vmcnt(11)" ::: "memory"); break;
    case 12: asm volatile("s_waitcnt vmcnt(12)" ::: "memory"); break;
    case 13: asm volatile("s_waitcnt vmcnt(13)" ::: "memory"); break;
    case 14: asm volatile("s_waitcnt vmcnt(14)" ::: "memory"); break;
    case 15: asm volatile("s_waitcnt vmcnt(15)" ::: "memory"); break;
    case 16: asm volatile("s_waitcnt vmcnt(16)" ::: "memory"); break;
    case 17: asm volatile("s_waitcnt vmcnt(17)" ::: "memory"); break;
    case 18: asm volatile("s_waitcnt vmcnt(18)" ::: "memory"); break;
    case 19: asm volatile("s_waitcnt vmcnt(19)" ::: "memory"); break;
    case 20: asm volatile("s_waitcnt vmcnt(20)" ::: "memory"); break;
    default: asm volatile("s_waitcnt vmcnt(0)"  ::: "memory"); break;
    }
}

// bit-mixed dim-group -> slot permutation (f32 kernel, 4-float groups)
__device__ __forceinline__ int dperm(int d) {
    return (d & 24) | ((d + 2 * (d >> 3)) & 7);
}
__device__ __forceinline__ int dperm_inv(int u) {
    int q = u >> 3;
    return (q << 3) | ((u - 2 * q) & 7);
}

// ---------------------------------------------------------------------------
// K1: merged setup. Blocks 0..511 (128 thr): W1 row j = blk, b_sum[j],
// const2[j] (h1 recomputed redundantly per block — removes the cross-kernel
// dependency); block 0 also writes c1/h1. Blocks >=512: row_ptr binary search.
// ---------------------------------------------------------------------------
__global__ __launch_bounds__(128) void setup_kernel(
    const int* __restrict__ n2g, int N_, int B_, int* __restrict__ row_ptr,
    const float* __restrict__ w_ih, const float* __restrict__ w_hh,
    const float* __restrict__ b_ih, const float* __restrict__ b_hh,
    float* __restrict__ W1, float* __restrict__ const2,
    float* __restrict__ b_sum, float* __restrict__ c1,
    float* __restrict__ h1) {
    int blk = blockIdx.x;
    if (blk < 512) {
        int j = blk, k = threadIdx.x;
        float w = w_ih[j * 256 + k] + w_hh[j * 128 + k];
        W1[j * 128 + k] = w;
        // h1[k], c1[k] from biases only (h=c=q*=0 at step 1)
        float bk = b_ih[k] + b_hh[k];
        float bg = b_ih[256 + k] + b_hh[256 + k];
        float bo = b_ih[384 + k] + b_hh[384 + k];
        float ig = 1.f / (1.f + __expf(-bk));
        float gg = tanhf(bg);
        float c  = ig * gg;
        float og = 1.f / (1.f + __expf(-bo));
        float h1k = og * tanhf(c);
        if (j == 0) { c1[k] = c; h1[k] = h1k; }
        __shared__ float red[128];
        red[k] = w * h1k;
        __syncthreads();
        for (int s = 64; s > 0; s >>= 1) {
            if (k < s) red[k] += red[k + s];
            __syncthreads();
        }
        if (k == 0) {
            float bs = b_ih[j] + b_hh[j];
            b_sum[j] = bs;
            const2[j] = bs + red[0];
        }
    } else {
        int b = (blk - 512) * 128 + threadIdx.x;
        if (b > B_) return;
        if (b == B_) { row_ptr[b] = N_; return; }
        int lo = 0, hi = N_;
        while (lo < hi) {
            int mid = (lo + hi) >> 1;
            if (n2g[mid] < b) lo = mid + 1; else hi = mid;
        }
        row_ptr[b] = lo;
    }
}

// ---------------------------------------------------------------------------
// K4: tiled GEMM, packed-fp16 v_dot2_f32_f16 inner loop, fp16 gates output.
// gates[b][j] = base[j] + A1[b]·Wa[j] (+ A2[b]·Wb[j])
// ---------------------------------------------------------------------------
#define BM 64
#define BN 64
#define BK 32
__global__ __launch_bounds__(256) void lstm_gemm_kernel(
    const float* __restrict__ A1, const float* __restrict__ Wa, int wa_stride,
    const float* __restrict__ A2, const float* __restrict__ Wb, int wb_stride,
    const float* __restrict__ base, _Float16* __restrict__ gates, int B_) {
    __shared__ float As[BM][BK / 2 + 1];   // packed half2
    __shared__ float Bs[BN][BK / 2 + 1];
    int b0 = blockIdx.y * BM;
    int j0 = blockIdx.x * BN;
    int tid = threadIdx.x;
    int tx = tid & 15, ty = tid >> 4;
    float acc[4][4] = {};
    int nphase = A2 ? 2 : 1;
    for (int phase = 0; phase < nphase; phase++) {
        const float* A = phase ? A2 : A1;
        const float* W = phase ? Wb : Wa;
        int ws = phase ? wb_stride : wa_stride;
        for (int k0 = 0; k0 < 128; k0 += BK) {
            __syncthreads();
            for (int i = tid; i < BM * (BK / 2); i += 256) {
                int r = i >> 4, cc = i & 15;
                int bb = b0 + r;
                float2 f2 = (bb < B_)
                    ? *(const float2*)&A[(size_t)bb * D + k0 + 2 * cc]
                    : make_float2(0.f, 0.f);
                hf2 h = {(_Float16)f2.x, (_Float16)f2.y};
                As[r][cc] = as_f32(h);
            }
            for (int i = tid; i < BN * (BK / 2); i += 256) {
                int r = i >> 4, cc = i & 15;
                float2 f2 = *(const float2*)&W[(size_t)(j0 + r) * ws + k0 + 2 * cc];
                hf2 h = {(_Float16)f2.x, (_Float16)f2.y};
                Bs[r][cc] = as_f32(h);
            }
            __syncthreads();
#pragma unroll
            for (int kk = 0; kk < BK / 2; kk++) {
                float av[4], bv[4];
#pragma unroll
                for (int i = 0; i < 4; i++) av[i] = As[ty * 4 + i][kk];
#pragma unroll
                for (int j = 0; j < 4; j++) bv[j] = Bs[tx * 4 + j][kk];
#pragma unroll
                for (int i = 0; i < 4; i++)
#pragma unroll
                    for (int j = 0; j < 4; j++)
                        acc[i][j] = fdot2f(as_hf2(av[i]), as_hf2(bv[j]),
                                           acc[i][j]);
            }
        }
    }
    for (int i = 0; i < 4; i++) {
        int bb = b0 + ty * 4 + i;
        if (bb >= B_) continue;
        for (int j = 0; j < 4; j++) {
            int jj = j0 + tx * 4 + j;
            gates[(size_t)bb * 512 + jj] = (_Float16)(acc[i][j] + base[jj]);
        }
    }
}

// ---------------------------------------------------------------------------
// K5: elementwise LSTM state update from fp16 gates
// ---------------------------------------------------------------------------
__global__ void lstm_elem_kernel(const _Float16* __restrict__ gates,
                                 const float* __restrict__ c_prev, int c_bcast,
                                 float* __restrict__ c_out,
                                 float* __restrict__ h_out, int B_) {
    int t = blockIdx.x * 256 + threadIdx.x;
    if (t >= B_ * D) return;
    int b = t >> 7, d = t & (D - 1);
    const _Float16* g = gates + (size_t)b * 512;
    float ig = 1.f / (1.f + __expf(-(float)g[d]));
    float fg = 1.f / (1.f + __expf(-(float)g[128 + d]));
    float gg = tanhf((float)g[256 + d]);
    float og = 1.f / (1.f + __expf(-(float)g[384 + d]));
    float cp = c_bcast ? c_prev[d] : c_prev[t];
    float c = fg * cp + ig * gg;
    c_out[t] = c;
    h_out[t] = og * tanhf(c);
}

// ---------------------------------------------------------------------------
// K6: f32 attention (R4 structure). fp16 emission of x fused into the
// ACCUMULATE loop: the acc-phase LDS read at slot (dperm(sc)+row)&31 is
// exactly x4[row][sc] (rotation cancels), so we convert+store those values
// directly — no extra LDS reads, 8x8B stores/lane/tile (ps += 8).
// ---------------------------------------------------------------------------
__global__ __launch_bounds__(256, 2) void attn_kernel(
    const float* __restrict__ x, const float* __restrict__ q_src, int q_bcast,
    const int* __restrict__ row_ptr, float* __restrict__ out,
    float* __restrict__ final_out, int B_, _Float16* __restrict__ xh) {

    __shared__ float xs[WPB][2][TILE * D];  // 2 x 8 KB per wave
    __shared__ float qs[WPB][2][256];       // 2 x 1 KB per wave
    __shared__ float wsh[WPB][TILE];

    const int tid  = threadIdx.x;
    const int wave = tid >> 6;
    const int lane = tid & 63;
    const int NW   = gridDim.x * WPB;

    const int p    = lane >> 5;        // staging/acc parity
    const int sc   = lane & 31;        // slot / dim-group id
    const int n    = lane >> 2;        // node id (dot): 0..15
    const int qd   = lane & 3;         // dim quarter (dot)
    const int qdb  = qd << 3;
    const int qd2  = qd << 1;
    const int dacc = dperm(sc);
    const int qsrc = dperm_inv(sc);

    float* xb[2] = {xs[wave][0], xs[wave][1]};
    float* qb[2] = {qs[wave][0], qs[wave][1]};
    float* wsw   = wsh[wave];

    auto issue_tile = [&](int t0, int e_, float* dst) {
#pragma unroll
        for (int j = 0; j < 8; j++) {
            int row = 2 * j + p;
            int rg  = t0 + row;
            rg = (rg < e_) ? rg : (e_ - 1);
            int u = (sc - row) & 31;
            int col = dperm_inv(u);
            gload16(x + ((size_t)rg * D + (col << 2)), dst + j * 256);
        }
    };
    auto issue_q = [&](int bq, float* dst) {
        const float* qp = q_bcast ? q_src : q_src + (size_t)bq * D;
        gload16(qp + (qsrc << 2), dst);
    };

    const int S = out ? 1 : 2;
    int b = blockIdx.x * WPB + wave;
    if (b >= B_) return;

    unsigned long long se0 = sload2(row_ptr, b);
    int s = (int)(se0 & 0xffffffffull), e = (int)(se0 >> 32);
    int cur = 0, qc = 0, ps = 0;
    issue_q(b, qb[0]);
    if (s < e) issue_tile(s, e, xb[0]);

    while (1) {
        float m = -1e30f, lsum = 0.f;
        float ax = 0.f, ay = 0.f, az = 0.f, aw = 0.f;
        int sn = 0, en = 0;
        int bn = b + NW;
        int have_next = (bn < B_);

        if (s < e) {
            for (int t0 = s; t0 < e; t0 += TILE) {
                int nt = e - t0; nt = (nt < TILE) ? nt : TILE;
                int just;
                if (t0 + TILE < e) {
                    issue_tile(t0 + TILE, e, xb[cur ^ 1]);
                    just = 8;
                } else if (have_next) {
                    unsigned long long se2 = sload2(row_ptr, bn);
                    sn = (int)(se2 & 0xffffffffull); en = (int)(se2 >> 32);
                    issue_q(bn, qb[qc ^ 1]);
                    just = 1;
                    if (sn < en) { issue_tile(sn, en, xb[cur ^ 1]); just = 9; }
                } else {
                    just = 0;
                }
                wait_vm(just + ps); ps = 0;

                const float4* xw4 = (const float4*)xb[cur];
                const float4* qw4 = (const float4*)qb[qc];

                // dot: 4 lanes/node, 32 dims each; 2 accumulators
                float pd0 = 0.f, pd1 = 0.f;
#pragma unroll
                for (int j = 0; j < 8; j += 2) {
                    int sl0 = ((qdb | ((j + qd2) & 7)) + n) & 31;
                    int sl1 = ((qdb | ((j + 1 + qd2) & 7)) + n) & 31;
                    float4 xv0 = xw4[(n << 5) + sl0];
                    float4 qv0 = qw4[qdb | ((j + qd2) & 7)];
                    float4 xv1 = xw4[(n << 5) + sl1];
                    float4 qv1 = qw4[qdb | ((j + 1 + qd2) & 7)];
                    pd0 += xv0.x * qv0.x + xv0.y * qv0.y + xv0.z * qv0.z + xv0.w * qv0.w;
                    pd1 += xv1.x * qv1.x + xv1.y * qv1.y + xv1.z * qv1.z + xv1.w * qv1.w;
                }
                float pd = pd0 + pd1;
                pd += __shfl_xor(pd, 1);
                pd += __shfl_xor(pd, 2);
                float prod = (n < nt) ? pd : -1e30f;

                if (!__all(prod <= m + THR)) {
                    float tmax = prod;
#pragma unroll
                    for (int mk = 4; mk <= 32; mk <<= 1)
                        tmax = fmaxf(tmax, __shfl_xor(tmax, mk));
                    float m_new = fmaxf(m, tmax);
                    float r = __expf(m - m_new);
                    lsum *= r;
                    ax *= r; ay *= r; az *= r; aw *= r;
                    m = m_new;
                }
                float w = __expf(prod - m);

                float tsum = w;
#pragma unroll
                for (int mk = 4; mk <= 32; mk <<= 1)
                    tsum += __shfl_xor(tsum, mk);
                lsum += tsum;

                if (qd == 0) wsw[n] = w;

                // accumulate; fused fp16 emission (content here IS x4[row][sc])
#pragma unroll
                for (int i = 0; i < 8; i++) {
                    int row = 2 * i + p;
                    float wt = wsw[row];
                    float4 xv = xw4[(row << 5) + ((dacc + row) & 31)];
                    if (xh) {
                        hf2 h0 = {(_Float16)xv.x, (_Float16)xv.y};
                        hf2 h1 = {(_Float16)xv.z, (_Float16)xv.w};
                        int rowg = t0 + row;
                        rowg = (rowg < e) ? rowg : (e - 1);  // idempotent
                        *(float2*)((char*)xh + ((size_t)rowg * 256 + (sc << 3)))
                            = make_float2(as_f32(h0), as_f32(h1));
                    }
                    ax += wt * xv.x; ay += wt * xv.y;
                    az += wt * xv.z; aw += wt * xv.w;
                }
                if (xh) ps += 8;
                cur ^= 1;
            }
        } else {
            int just = 0;
            if (have_next) {
                unsigned long long se2 = sload2(row_ptr, bn);
                sn = (int)(se2 & 0xffffffffull); en = (int)(se2 >> 32);
                issue_q(bn, qb[qc ^ 1]);
                just = 1;
                if (sn < en) { issue_tile(sn, en, xb[cur ^ 1]); just = 9; cur ^= 1; }
            }
            wait_vm(just + ps); ps = 0;
        }

        // finalize graph b
        ax += __shfl_xor(ax, 32);
        ay += __shfl_xor(ay, 32);
        az += __shfl_xor(az, 32);
        aw += __shfl_xor(aw, 32);
        float inv = 1.f / (lsum + EPS);
        float4 o = {ax * inv, ay * inv, az * inv, aw * inv};
        if (p == 0) {
            if (out) {
                ((float4*)out)[(size_t)b * 32 + sc] = o;
            } else {
                const float4* q4r = (const float4*)qb[qc];
                float4 qv = q4r[dperm(sc)];
                float4* fo = (float4*)(final_out + (size_t)b * 256);
                fo[sc] = qv;
                fo[32 + sc] = o;
            }
        }
        ps += S;
        if (!have_next) break;
        b = bn; s = sn; e = en; qc ^= 1;
    }
}

// ---------------------------------------------------------------------------
// K7: fp16 attention (passes 2-3). TILE_H=32 rows (8 KB tiles, 8 gloads in
// flight). Rotation layout in 16B groups; v_dot2_f32_f16 dot; f32 accum.
// ---------------------------------------------------------------------------
__global__ __launch_bounds__(256, 2) void attn_h_kernel(
    const _Float16* __restrict__ xh, const float* __restrict__ q_src,
    const int* __restrict__ row_ptr, float* __restrict__ out,
    float* __restrict__ final_out, int B_) {

    __shared__ float xs[WPB][2][TILE_H * 64];  // 2 x 8 KB per wave
    __shared__ float qf[WPB][2][256];          // staged q f32 (1 KB incl dup)
    __shared__ float qh[WPB][64];              // q as half2 (256 B)
    __shared__ float wsh[WPB][TILE_H];

    const int tid  = threadIdx.x;
    const int wave = tid >> 6;
    const int lane = tid & 63;
    const int NW   = gridDim.x * WPB;

    const int n  = lane >> 1;    // dot: node 0..31
    const int h  = lane & 1;     // dot: dim half
    const int h8 = h << 3;
    const int g  = lane & 15;    // acc: 16B group (8 dims)
    const int pp = lane >> 4;    // acc: row phase 0..3

    float* xb[2] = {xs[wave][0], xs[wave][1]};
    float* qb[2] = {qf[wave][0], qf[wave][1]};
    float* qhw   = qh[wave];
    float* wsw   = wsh[wave];

    auto issue_tile = [&](int t0, int e_, float* dst) {
#pragma unroll
        for (int j = 0; j < 8; j++) {
            int idx = (j << 6) + lane;           // 0..511 slots
            int row = idx >> 4, s16 = idx & 15;
            int rg = t0 + row;
            rg = (rg < e_) ? rg : (e_ - 1);
            int gg = (s16 - row) & 15;           // pre-swizzled source group
            gload16((const char*)xh + ((size_t)rg << 8) + (gg << 4),
                    dst + (j << 8));
        }
    };
    auto issue_q = [&](int bq, float* dst) {
        gload16(q_src + ((size_t)bq << 7) + ((lane & 31) << 2), dst);
    };

    const int S = out ? 2 : 4;
    int b = blockIdx.x * WPB + wave;
    if (b >= B_) return;

    unsigned long long se0 = sload2(row_ptr, b);
    int s = (int)(se0 & 0xffffffffull), e = (int)(se0 >> 32);
    int cur = 0, qc = 0, ps = 0;
    issue_q(b, qb[0]);
    if (s < e) issue_tile(s, e, xb[0]);

    while (1) {
        float m = -1e30f, lsum = 0.f;
        float a[8] = {0.f, 0.f, 0.f, 0.f, 0.f, 0.f, 0.f, 0.f};
        int sn = 0, en = 0;
        int bn = b + NW;
        int have_next = (bn < B_);

        if (s < e) {
            for (int t0 = s; t0 < e; t0 += TILE_H) {
                int nt = e - t0; nt = (nt < TILE_H) ? nt : TILE_H;
                int just;
                if (t0 + TILE_H < e) {
                    issue_tile(t0 + TILE_H, e, xb[cur ^ 1]);
                    just = 8;
                } else if (have_next) {
                    unsigned long long se2 = sload2(row_ptr, bn);
                    sn = (int)(se2 & 0xffffffffull); en = (int)(se2 >> 32);
                    issue_q(bn, qb[qc ^ 1]);
                    just = 1;
                    if (sn < en) { issue_tile(sn, en, xb[cur ^ 1]); just = 9; }
                } else {
                    just = 0;
                }
                wait_vm(just + ps); ps = 0;

                if (t0 == s) {  // convert this graph's q: f32 -> half2
                    float2 f2 = ((const float2*)qb[qc])[lane];
                    hf2 hq = {(_Float16)f2.x, (_Float16)f2.y};
                    qhw[lane] = as_f32(hq);
                }

                const float4* xw4 = (const float4*)xb[cur];
                const float4* qh4 = (const float4*)qhw;

                // dot: 2 lanes/node, 64 dims each via fdot2
                float pd0 = 0.f, pd1 = 0.f;
#pragma unroll
                for (int j = 0; j < 8; j++) {
                    int gg = h8 + j;
                    float4 xv = xw4[(n << 4) + ((gg + n) & 15)];
                    float4 qv = qh4[gg];
                    pd0 = fdot2f(as_hf2(xv.x), as_hf2(qv.x), pd0);
                    pd1 = fdot2f(as_hf2(xv.y), as_hf2(qv.y), pd1);
                    pd0 = fdot2f(as_hf2(xv.z), as_hf2(qv.z), pd0);
                    pd1 = fdot2f(as_hf2(xv.w), as_hf2(qv.w), pd1);
                }
                float pd = pd0 + pd1;
                pd += __shfl_xor(pd, 1);
                float prod = (n < nt) ? pd : -1e30f;

                if (!__all(prod <= m + THR)) {
                    float tmax = prod;
#pragma unroll
                    for (int mk = 2; mk <= 32; mk <<= 1)
                        tmax = fmaxf(tmax, __shfl_xor(tmax, mk));
                    float m_new = fmaxf(m, tmax);
                    float r = __expf(m - m_new);
                    lsum *= r;
#pragma unroll
                    for (int k = 0; k < 8; k++) a[k] *= r;
                    m = m_new;
                }
                float w = __expf(prod - m);

                float tsum = w;
#pragma unroll
                for (int mk = 2; mk <= 32; mk <<= 1)
                    tsum += __shfl_xor(tsum, mk);
                lsum += tsum;

                if (h == 0) wsw[n] = w;

                // accumulate: lane owns group g (8 dims), rows 4i+pp
#pragma unroll
                for (int i = 0; i < 8; i++) {
                    int ro = (i << 2) + pp;
                    float wt = wsw[ro];
                    float4 xv = xw4[(ro << 4) + ((g + ro) & 15)];
                    hf2 h0 = as_hf2(xv.x), h1 = as_hf2(xv.y);
                    hf2 h2 = as_hf2(xv.z), h3 = as_hf2(xv.w);
                    a[0] += wt * (float)h0.x; a[1] += wt * (float)h0.y;
                    a[2] += wt * (float)h1.x; a[3] += wt * (float)h1.y;
                    a[4] += wt * (float)h2.x; a[5] += wt * (float)h2.y;
                    a[6] += wt * (float)h3.x; a[7] += wt * (float)h3.y;
                }
                cur ^= 1;
            }
        } else {
            int just = 0;
            if (have_next) {
                unsigned long long se2 = sload2(row_ptr, bn);
                sn = (int)(se2 & 0xffffffffull); en = (int)(se2 >> 32);
                issue_q(bn, qb[qc ^ 1]);
                just = 1;
                if (sn < en) { issue_tile(sn, en, xb[cur ^ 1]); just = 9; cur ^= 1; }
            }
            wait_vm(just + ps); ps = 0;
        }

        // finalize graph b: reduce over pp (4 lanes per group)
#pragma unroll
        for (int k = 0; k < 8; k++) {
            a[k] += __shfl_xor(a[k], 16);
            a[k] += __shfl_xor(a[k], 32);
        }
        float inv = 1.f / (lsum + EPS);
        if (pp == 0) {
            float4 o0 = {a[0] * inv, a[1] * inv, a[2] * inv, a[3] * inv};
            float4 o1 = {a[4] * inv, a[5] * inv, a[6] * inv, a[7] * inv};
            if (out) {
                float4* op = (float4*)(out + (size_t)b * D + (g << 3));
                op[0] = o0; op[1] = o1;
            } else {
                const float4* q4r = (const float4*)qb[qc];
                float4 q0 = q4r[g * 2], q1 = q4r[g * 2 + 1];
                float4* fo = (float4*)(final_out + (size_t)b * 256 + (g << 3));
                fo[0] = q0; fo[1] = q1;
                float4* fo2 = (float4*)(final_out + (size_t)b * 256 + D + (g << 3));
                fo2[0] = o0; fo2[1] = o1;
            }
        }
        ps += S;
        if (!have_next) break;
        b = bn; s = sn; e = en; qc ^= 1;
    }
}

// ---------------------------------------------------------------------------
extern "C" void kernel_launch(void* const* d_in, const int* in_sizes, int n_in,
                              void* d_out, int out_size, void* d_ws,
                              size_t ws_size, hipStream_t stream) {
    const float* x    = (const float*)d_in[0];
    const float* w_ih = (const float*)d_in[1];
    const float* w_hh = (const float*)d_in[2];
    const float* b_ih = (const float*)d_in[3];
    const float* b_hh = (const float*)d_in[4];
    const int*   n2g  = (const int*)d_in[5];

    int N_ = in_sizes[0] / D;     // 1,000,000
    int B_ = out_size / (2 * D);  // 10,000

    char* wsb = (char*)d_ws;
    size_t off = 0;
    auto carve = [&](size_t bytes) {
        void* pp = wsb + off;
        off = (off + bytes + 255) & ~(size_t)255;
        return pp;
    };
    int*   row_ptr  = (int*)carve((size_t)(B_ + 1) * 4);
    float* b_sum    = (float*)carve(512 * 4);
    float* c1       = (float*)carve(D * 4);
    float* h1       = (float*)carve(D * 4);
    float* const2   = (float*)carve(512 * 4);
    float* W1       = (float*)carve((size_t)512 * D * 4);
    float* hbuf     = (float*)carve((size_t)B_ * D * 4);
    float* cbuf     = (float*)carve((size_t)B_ * D * 4);
    float* outbuf   = (float*)carve((size_t)B_ * D * 4);
    _Float16* gates = (_Float16*)carve((size_t)B_ * 512 * 2);
    _Float16* xh    = (_Float16*)carve((size_t)N_ * D * 2);   // 256 MB
    bool use_half = (off <= ws_size);

    const float* W2 = w_ih + D;  // rows of w_ih, col offset 128, stride 256

    int sgrid = 512 + (B_ + 1 + 127) / 128;
    setup_kernel<<<sgrid, 128, 0, stream>>>(n2g, N_, B_, row_ptr, w_ih, w_hh,
                                            b_ih, b_hh, W1, const2, b_sum,
                                            c1, h1);

    dim3 ggrid(512 / BN, (B_ + BM - 1) / BM);
    int  egrid = (B_ * D + 255) / 256;

    if (use_half) {
        // pass 1 (f32, fused fp16 emission)
        attn_kernel<<<NBLK, 256, 0, stream>>>(x, h1, 1, row_ptr, outbuf,
                                              nullptr, B_, xh);
        lstm_gemm_kernel<<<ggrid, 256, 0, stream>>>(outbuf, W2, 256, nullptr,
                                                    nullptr, 0, const2, gates, B_);
        lstm_elem_kernel<<<egrid, 256, 0, stream>>>(gates, c1, 1, cbuf, hbuf, B_);
        // pass 2 (fp16)
        attn_h_kernel<<<NBLK_H, 256, 0, stream>>>(xh, hbuf, row_ptr, outbuf,
                                                  nullptr, B_);
        lstm_gemm_kernel<<<ggrid, 256, 0, stream>>>(hbuf, W1, 128, outbuf, W2, 256,
                                                    b_sum, gates, B_);
        lstm_elem_kernel<<<egrid, 256, 0, stream>>>(gates, cbuf, 0, cbuf, hbuf, B_);
        // pass 3 (fp16, writes q_star)
        attn_h_kernel<<<NBLK_H, 256, 0, stream>>>(xh, hbuf, row_ptr, nullptr,
                                                  (float*)d_out, B_);
    } else {
        // fallback: all-f32 attention sequence
        attn_kernel<<<NBLK, 256, 0, stream>>>(x, h1, 1, row_ptr, outbuf,
                                              nullptr, B_, nullptr);
        lstm_gemm_kernel<<<ggrid, 256, 0, stream>>>(outbuf, W2, 256, nullptr,
                                                    nullptr, 0, const2, gates, B_);
        lstm_elem_kernel<<<egrid, 256, 0, stream>>>(gates, c1, 1, cbuf, hbuf, B_);
        attn_kernel<<<NBLK, 256, 0, stream>>>(x, hbuf, 0, row_ptr, outbuf,
                                              nullptr, B_, nullptr);
        lstm_gemm_kernel<<<ggrid, 256, 0, stream>>>(hbuf, W1, 128, outbuf, W2, 256,
                                                    b_sum, gates, B_);
        lstm_elem_kernel<<<egrid, 256, 0, stream>>>(gates, cbuf, 0, cbuf, hbuf, B_);
        attn_kernel<<<NBLK, 256, 0, stream>>>(x, hbuf, 0, row_ptr, nullptr,
                                              (float*)d_out, B_, nullptr);
    }
}